// Round 2
// baseline (713.411 us; speedup 1.0000x reference)
//
#include <hip/hip_runtime.h>

typedef unsigned short u16;
typedef unsigned int u32;

#define BATCH 4
#define NTOK 4096
#define SCALE_ATTN 0.125f

typedef float f32x4 __attribute__((ext_vector_type(4)));
typedef __bf16 bf16x8 __attribute__((ext_vector_type(8)));

__device__ __forceinline__ float b2f(u16 s) { return __uint_as_float(((u32)s) << 16); }
__device__ __forceinline__ u16 f2bf(float f) {
    u32 u = __float_as_uint(f);
    u += 0x7FFFu + ((u >> 16) & 1u);
    return (u16)(u >> 16);
}
__device__ __forceinline__ u32 pk2(float x, float y) {
    return (u32)f2bf(x) | ((u32)f2bf(y) << 16);
}
__device__ __forceinline__ uint4 pack8(float4 a, float4 b) {
    uint4 r;
    r.x = pk2(a.x, a.y); r.y = pk2(a.z, a.w);
    r.z = pk2(b.x, b.y); r.w = pk2(b.z, b.w);
    return r;
}
__device__ __forceinline__ f32x4 mfma16(uint4 a, uint4 b, f32x4 c) {
    return __builtin_amdgcn_mfma_f32_16x16x32_bf16(
        __builtin_bit_cast(bf16x8, a), __builtin_bit_cast(bf16x8, b), c, 0, 0, 0);
}

// ---------------------------------------------------------------------------
// GEMM: C[M,N](bf16) = A[M,K] @ B[N,K]^T + bias(f32), optional ReLU.
// A is f32 (original input) or bf16 (intermediate) per a_bf flag. B/bias f32.
// 128x128 tile, BK=64, 256 threads (4 waves, 2x2 of 64x64), mfma 16x16x32 bf16.
// ---------------------------------------------------------------------------
__global__ __launch_bounds__(256) void gemm_bt_kernel(
    const void* __restrict__ A, const float* __restrict__ B,
    const float* __restrict__ bias, u16* __restrict__ C,
    int M, int N, int K, int relu, int a_bf)
{
    __shared__ u16 As[128][72];  // +8 pad; row stride 144 B (16B-aligned)
    __shared__ u16 Bs[128][72];
    const int tid = threadIdx.x;
    const int m0 = blockIdx.y * 128;
    const int n0 = blockIdx.x * 128;
    const int wave = tid >> 6, lane = tid & 63;
    const int wm = (wave >> 1) * 64, wn = (wave & 1) * 64;
    const int lm = lane & 15, quad = lane >> 4;

    f32x4 acc[4][4] = {};

    for (int k0 = 0; k0 < K; k0 += 64) {
        #pragma unroll
        for (int t = 0; t < 4; ++t) {
            int c = tid + t * 256;            // 0..1023
            int row = c >> 3, col = (c & 7) * 8;
            uint4 av;
            if (a_bf) {
                av = *(const uint4*)((const u16*)A + (size_t)(m0 + row) * K + k0 + col);
            } else {
                const float* ap = (const float*)A + (size_t)(m0 + row) * K + k0 + col;
                av = pack8(*(const float4*)ap, *(const float4*)(ap + 4));
            }
            *(uint4*)(&As[row][col]) = av;
            const float* bp = B + (size_t)(n0 + row) * K + k0 + col;
            *(uint4*)(&Bs[row][col]) = pack8(*(const float4*)bp, *(const float4*)(bp + 4));
        }
        __syncthreads();
        #pragma unroll
        for (int kk = 0; kk < 2; ++kk) {
            uint4 af[4], bf[4];
            #pragma unroll
            for (int i = 0; i < 4; ++i)
                af[i] = *(const uint4*)(&As[wm + i * 16 + lm][kk * 32 + quad * 8]);
            #pragma unroll
            for (int j = 0; j < 4; ++j)
                bf[j] = *(const uint4*)(&Bs[wn + j * 16 + lm][kk * 32 + quad * 8]);
            #pragma unroll
            for (int i = 0; i < 4; ++i)
                #pragma unroll
                for (int j = 0; j < 4; ++j)
                    acc[i][j] = mfma16(af[i], bf[j], acc[i][j]);
        }
        __syncthreads();
    }

    #pragma unroll
    for (int j = 0; j < 4; ++j) {
        int cg = n0 + wn + j * 16 + lm;
        float bv = bias ? bias[cg] : 0.f;
        #pragma unroll
        for (int i = 0; i < 4; ++i) {
            #pragma unroll
            for (int r = 0; r < 4; ++r) {
                int rg = m0 + wm + i * 16 + quad * 4 + r;
                float v = acc[i][j][r] + bv;
                if (relu) v = fmaxf(v, 0.f);
                C[(size_t)rg * N + cg] = f2bf(v);
            }
        }
    }
}

// ---------------------------------------------------------------------------
// Fused residual add + LayerNorm over D=512. One block (256 thr) per row.
// out = LN(a + r) * g + b.  a: bf16. r: f32 or bf16. out: f32 or bf16.
// ---------------------------------------------------------------------------
__global__ __launch_bounds__(256) void add_ln_kernel(
    const u16* __restrict__ a, const void* __restrict__ r,
    const float* __restrict__ g, const float* __restrict__ be,
    void* __restrict__ out, int r_f32, int out_f32)
{
    const int row = blockIdx.x, tid = threadIdx.x;
    u32 av = *(const u32*)(a + (size_t)row * 512 + tid * 2);
    float r0, r1;
    if (r_f32) {
        float2 rv = *(const float2*)((const float*)r + (size_t)row * 512 + tid * 2);
        r0 = rv.x; r1 = rv.y;
    } else {
        u32 rv = *(const u32*)((const u16*)r + (size_t)row * 512 + tid * 2);
        r0 = b2f((u16)(rv & 0xFFFFu)); r1 = b2f((u16)(rv >> 16));
    }
    float v0 = b2f((u16)(av & 0xFFFFu)) + r0;
    float v1 = b2f((u16)(av >> 16)) + r1;
    float s = v0 + v1, q = v0 * v0 + v1 * v1;
    #pragma unroll
    for (int m = 1; m < 64; m <<= 1) { s += __shfl_xor(s, m); q += __shfl_xor(q, m); }
    __shared__ float ss[4], qq[4];
    int wave = tid >> 6, lane = tid & 63;
    if (lane == 0) { ss[wave] = s; qq[wave] = q; }
    __syncthreads();
    s = ss[0] + ss[1] + ss[2] + ss[3];
    q = qq[0] + qq[1] + qq[2] + qq[3];
    float mean = s * (1.f / 512.f);
    float var = q * (1.f / 512.f) - mean * mean;
    float rstd = rsqrtf(var + 1e-5f);
    float2 gv = *(const float2*)(g + tid * 2);
    float2 bv = *(const float2*)(be + tid * 2);
    float o0 = (v0 - mean) * rstd * gv.x + bv.x;
    float o1 = (v1 - mean) * rstd * gv.y + bv.y;
    if (out_f32) {
        float2 ov; ov.x = o0; ov.y = o1;
        *(float2*)((float*)out + (size_t)row * 512 + tid * 2) = ov;
    } else {
        *(u32*)((u16*)out + (size_t)row * 512 + tid * 2) = pk2(o0, o1);
    }
}

// ---------------------------------------------------------------------------
// Self-attention (full, no mask), flash-style online softmax. All bf16 I/O.
// qkv layout: [t*B+b][1536] = [q(512) | k(512) | v(512)], head h at +h*64.
// Block = 256 thr handles (16 q-rows, one bh). 256-key chunks.
// ---------------------------------------------------------------------------
__global__ __launch_bounds__(256) void self_attn_kernel(
    const u16* __restrict__ qkv, u16* __restrict__ o)
{
    const int qb = blockIdx.x;          // 0..63
    const int bh = blockIdx.y;          // 0..31
    const int b = bh >> 3, h = bh & 7;
    const int tid = threadIdx.x;
    const int lane = tid & 63, wave = tid >> 6;
    const int lm = lane & 15, quad = lane >> 4;

    __shared__ float sc[16][261];

    const int tq = qb * 16 + lm;
    const u16* qp = qkv + ((size_t)tq * BATCH + b) * 1536 + h * 64;
    uint4 a0 = *(const uint4*)(qp + quad * 8);
    uint4 a1 = *(const uint4*)(qp + 32 + quad * 8);

    const int qrow = tid >> 4, c16 = tid & 15;
    float m_i = -3.0e38f, l_i = 0.f;
    float acc0 = 0.f, acc1 = 0.f, acc2 = 0.f, acc3 = 0.f;
    const u16* vbase = qkv + (size_t)b * 1536 + 1024 + h * 64 + c16 * 4;

    for (int c = 0; c < 1024; c += 256) {
        #pragma unroll
        for (int kt = 0; kt < 4; ++kt) {
            int kcol = (wave * 4 + kt) * 16 + lm;
            int key = c + kcol;
            const u16* kp = qkv + ((size_t)key * BATCH + b) * 1536 + 512 + h * 64;
            uint4 b0 = *(const uint4*)(kp + quad * 8);
            uint4 b1 = *(const uint4*)(kp + 32 + quad * 8);
            f32x4 s4 = {};
            s4 = mfma16(a0, b0, s4);
            s4 = mfma16(a1, b1, s4);
            #pragma unroll
            for (int r = 0; r < 4; ++r) sc[quad * 4 + r][kcol] = s4[r] * SCALE_ATTN;
        }
        __syncthreads();
        float sv[16];
        float mloc = -3.0e38f;
        #pragma unroll
        for (int i = 0; i < 16; ++i) {
            sv[i] = sc[qrow][c16 + i * 16];
            mloc = fmaxf(mloc, sv[i]);
        }
        #pragma unroll
        for (int msk = 1; msk < 16; msk <<= 1) mloc = fmaxf(mloc, __shfl_xor(mloc, msk));
        float mnew = fmaxf(m_i, mloc);
        float alpha = __expf(m_i - mnew);
        float psum = 0.f;
        #pragma unroll
        for (int i = 0; i < 16; ++i) {
            float p = __expf(sv[i] - mnew);
            sc[qrow][c16 + i * 16] = p;
            psum += p;
        }
        #pragma unroll
        for (int msk = 1; msk < 16; msk <<= 1) psum += __shfl_xor(psum, msk);
        l_i = l_i * alpha + psum;
        m_i = mnew;
        acc0 *= alpha; acc1 *= alpha; acc2 *= alpha; acc3 *= alpha;
        for (int k = 0; k < 256; k += 2) {
            float p0 = sc[qrow][k];
            float p1 = sc[qrow][k + 1];
            const u16* vp = vbase + (size_t)(c + k) * 6144;
            uint2 w0 = *(const uint2*)vp;
            uint2 w1 = *(const uint2*)(vp + 6144);
            acc0 += p0 * b2f((u16)(w0.x & 0xFFFFu));
            acc1 += p0 * b2f((u16)(w0.x >> 16));
            acc2 += p0 * b2f((u16)(w0.y & 0xFFFFu));
            acc3 += p0 * b2f((u16)(w0.y >> 16));
            acc0 += p1 * b2f((u16)(w1.x & 0xFFFFu));
            acc1 += p1 * b2f((u16)(w1.x >> 16));
            acc2 += p1 * b2f((u16)(w1.y & 0xFFFFu));
            acc3 += p1 * b2f((u16)(w1.y >> 16));
        }
        __syncthreads();
    }
    float inv = 1.f / l_i;
    int to = qb * 16 + qrow;
    u16* op = o + ((size_t)to * BATCH + b) * 512 + h * 64 + c16 * 4;
    uint2 out2;
    out2.x = pk2(acc0 * inv, acc1 * inv);
    out2.y = pk2(acc2 * inv, acc3 * inv);
    *(uint2*)op = out2;
}

// ---------------------------------------------------------------------------
// Sliding-window cross attention: band |i-j|<=16 (33 keys). One thread per
// (t,b,h). bf16 I/O.
// ---------------------------------------------------------------------------
__global__ __launch_bounds__(256) void sw_attn_kernel(
    const u16* __restrict__ q2, const u16* __restrict__ k2,
    const u16* __restrict__ v2, u16* __restrict__ o)
{
    const int idx = blockIdx.x * 256 + threadIdx.x;   // (t*B+b)*8 + h
    const int h = idx & 7;
    const int tb = idx >> 3;
    const int b = tb & 3;
    const int t = tb >> 2;
    const u16* qp = q2 + (size_t)tb * 512 + h * 64;

    float q[64];
    #pragma unroll
    for (int d8 = 0; d8 < 8; ++d8) {
        uint4 u = *(const uint4*)(qp + d8 * 8);
        q[d8 * 8 + 0] = b2f((u16)(u.x & 0xFFFFu)); q[d8 * 8 + 1] = b2f((u16)(u.x >> 16));
        q[d8 * 8 + 2] = b2f((u16)(u.y & 0xFFFFu)); q[d8 * 8 + 3] = b2f((u16)(u.y >> 16));
        q[d8 * 8 + 4] = b2f((u16)(u.z & 0xFFFFu)); q[d8 * 8 + 5] = b2f((u16)(u.z >> 16));
        q[d8 * 8 + 6] = b2f((u16)(u.w & 0xFFFFu)); q[d8 * 8 + 7] = b2f((u16)(u.w >> 16));
    }
    __shared__ float sbuf[256][33];
    float* s = sbuf[threadIdx.x];

    float mx = -3.0e38f;
    for (int w = 0; w < 33; ++w) {
        int j = t - 16 + w;
        bool valid = (j >= 0) && (j < 1024);
        int jc = valid ? j : 0;
        const u16* kp = k2 + ((size_t)jc * BATCH + b) * 512 + h * 64;
        float acc = 0.f;
        #pragma unroll
        for (int d8 = 0; d8 < 8; ++d8) {
            uint4 u = *(const uint4*)(kp + d8 * 8);
            acc += q[d8 * 8 + 0] * b2f((u16)(u.x & 0xFFFFu));
            acc += q[d8 * 8 + 1] * b2f((u16)(u.x >> 16));
            acc += q[d8 * 8 + 2] * b2f((u16)(u.y & 0xFFFFu));
            acc += q[d8 * 8 + 3] * b2f((u16)(u.y >> 16));
            acc += q[d8 * 8 + 4] * b2f((u16)(u.z & 0xFFFFu));
            acc += q[d8 * 8 + 5] * b2f((u16)(u.z >> 16));
            acc += q[d8 * 8 + 6] * b2f((u16)(u.w & 0xFFFFu));
            acc += q[d8 * 8 + 7] * b2f((u16)(u.w >> 16));
        }
        float svw = valid ? acc * SCALE_ATTN : -3.0e38f;
        s[w] = svw;
        mx = fmaxf(mx, svw);
    }
    float l = 0.f;
    for (int w = 0; w < 33; ++w) {
        float p = __expf(s[w] - mx);
        s[w] = p;
        l += p;
    }
    float inv = 1.f / l;

    float ov[64];
    #pragma unroll
    for (int d = 0; d < 64; ++d) ov[d] = 0.f;
    for (int w = 0; w < 33; ++w) {
        int j = t - 16 + w;
        int jc = j < 0 ? 0 : (j > 1023 ? 1023 : j);
        float p = s[w];
        const u16* vp = v2 + ((size_t)jc * BATCH + b) * 512 + h * 64;
        #pragma unroll
        for (int d8 = 0; d8 < 8; ++d8) {
            uint4 u = *(const uint4*)(vp + d8 * 8);
            ov[d8 * 8 + 0] += p * b2f((u16)(u.x & 0xFFFFu));
            ov[d8 * 8 + 1] += p * b2f((u16)(u.x >> 16));
            ov[d8 * 8 + 2] += p * b2f((u16)(u.y & 0xFFFFu));
            ov[d8 * 8 + 3] += p * b2f((u16)(u.y >> 16));
            ov[d8 * 8 + 4] += p * b2f((u16)(u.z & 0xFFFFu));
            ov[d8 * 8 + 5] += p * b2f((u16)(u.z >> 16));
            ov[d8 * 8 + 6] += p * b2f((u16)(u.w & 0xFFFFu));
            ov[d8 * 8 + 7] += p * b2f((u16)(u.w >> 16));
        }
    }
    u16* op = o + (size_t)tb * 512 + h * 64;
    #pragma unroll
    for (int d2 = 0; d2 < 32; ++d2) {
        *(u32*)(op + d2 * 2) = pk2(ov[2 * d2] * inv, ov[2 * d2 + 1] * inv);
    }
}

// ---------------------------------------------------------------------------
// Host orchestration
// ---------------------------------------------------------------------------
static inline void gemm(hipStream_t st, const void* A, const float* B, const float* bias,
                        u16* C, int M, int N, int K, int relu, int a_bf)
{
    dim3 g(N / 128, M / 128);
    gemm_bt_kernel<<<g, dim3(256), 0, st>>>(A, B, bias, C, M, N, K, relu, a_bf);
}

extern "C" void kernel_launch(void* const* d_in, const int* in_sizes, int n_in,
                              void* d_out, int out_size, void* d_ws, size_t ws_size,
                              hipStream_t stream)
{
    const float* tgt        = (const float*)d_in[0];
    const float* memory     = (const float*)d_in[1];
    const float* in_proj_w  = (const float*)d_in[2];
    const float* in_proj_b  = (const float*)d_in[3];
    const float* out_proj_w = (const float*)d_in[4];
    const float* out_proj_b = (const float*)d_in[5];
    const float* sw_q_w = (const float*)d_in[6];
    const float* sw_q_b = (const float*)d_in[7];
    const float* sw_k_w = (const float*)d_in[8];
    const float* sw_k_b = (const float*)d_in[9];
    const float* sw_v_w = (const float*)d_in[10];
    const float* sw_v_b = (const float*)d_in[11];
    const float* sw_o_w = (const float*)d_in[12];
    const float* sw_o_b = (const float*)d_in[13];
    const float* lin1_w = (const float*)d_in[14];
    const float* lin1_b = (const float*)d_in[15];
    const float* lin2_w = (const float*)d_in[16];
    const float* lin2_b = (const float*)d_in[17];
    const float* n1_g = (const float*)d_in[18];
    const float* n1_b = (const float*)d_in[19];
    const float* n2_g = (const float*)d_in[20];
    const float* n2_b = (const float*)d_in[21];
    const float* n3_g = (const float*)d_in[22];
    const float* n3_b = (const float*)d_in[23];

    u16* ws = (u16*)d_ws;
    // bf16 workspace layout (u16 elems):
    // [qkv 6291456 | x1 2097152 | bufA 2097152 | bufB 2097152 | x2 2097152]
    u16* qkv  = ws;
    u16* x1   = ws + 6291456;
    u16* bufA = ws + 8388608;
    u16* bufB = ws + 10485760;
    u16* x2   = ws + 12582912;
    u16* q2 = qkv;               // reuse qkv region after self-attn
    u16* k2 = qkv + 2097152;
    u16* v2 = qkv + 4194304;
    u16* hbuf = qkv;             // 8388608 elems, spans qkv+x1 (both dead)

    // 1. QKV projection (A = tgt f32)
    gemm(stream, tgt, in_proj_w, in_proj_b, qkv, NTOK, 1536, 512, 0, 0);
    // 2. self attention
    self_attn_kernel<<<dim3(64, 32), dim3(256), 0, stream>>>(qkv, bufA);
    // 3. output projection (A = bufA bf16)
    gemm(stream, bufA, out_proj_w, out_proj_b, bufB, NTOK, 512, 512, 0, 1);
    // 4. x1 = LN1(bufB + tgt_f32) -> bf16
    add_ln_kernel<<<dim3(NTOK), dim3(256), 0, stream>>>(bufB, tgt, n1_g, n1_b, x1, 1, 0);
    // 5-7. sliding-window projections
    gemm(stream, x1, sw_q_w, sw_q_b, q2, NTOK, 512, 512, 0, 1);
    gemm(stream, memory, sw_k_w, sw_k_b, k2, NTOK, 512, 512, 0, 0);
    gemm(stream, memory, sw_v_w, sw_v_b, v2, NTOK, 512, 512, 0, 0);
    // 8. sliding-window attention
    sw_attn_kernel<<<dim3(128), dim3(256), 0, stream>>>(q2, k2, v2, bufA);
    // 9. sw output projection
    gemm(stream, bufA, sw_o_w, sw_o_b, bufB, NTOK, 512, 512, 0, 1);
    // 10. x2 = LN2(bufB + x1_bf16) -> bf16
    add_ln_kernel<<<dim3(NTOK), dim3(256), 0, stream>>>(bufB, x1, n2_g, n2_b, x2, 0, 0);
    // 11. FFN up + ReLU (A = x2 bf16)
    gemm(stream, x2, lin1_w, lin1_b, hbuf, NTOK, 2048, 512, 1, 1);
    // 12. FFN down (A = hbuf bf16, K=2048)
    gemm(stream, hbuf, lin2_w, lin2_b, bufA, NTOK, 512, 2048, 0, 1);
    // 13. out = LN3(bufA + x2_bf16) -> f32 d_out
    add_ln_kernel<<<dim3(NTOK), dim3(256), 0, stream>>>(bufA, x2, n3_g, n3_b, d_out, 0, 1);
}

// Round 3
// 498.929 us; speedup vs baseline: 1.4299x; 1.4299x over previous
//
#include <hip/hip_runtime.h>

typedef unsigned short u16;
typedef unsigned int u32;

#define BATCH 4
#define NTOK 4096
#define SCALE_ATTN 0.125f

typedef float f32x4 __attribute__((ext_vector_type(4)));
typedef __bf16 bf16x8 __attribute__((ext_vector_type(8)));

__device__ __forceinline__ float b2f(u16 s) { return __uint_as_float(((u32)s) << 16); }
__device__ __forceinline__ u16 f2bf(float f) {
    u32 u = __float_as_uint(f);
    u += 0x7FFFu + ((u >> 16) & 1u);
    return (u16)(u >> 16);
}
__device__ __forceinline__ u32 pk2(float x, float y) {
    return (u32)f2bf(x) | ((u32)f2bf(y) << 16);
}
// truncating pack (for attention probabilities; <=0.4% bias, fine vs 10% budget)
__device__ __forceinline__ u32 pk2t(float x, float y) {
    return (__float_as_uint(x) >> 16) | (__float_as_uint(y) & 0xFFFF0000u);
}
__device__ __forceinline__ uint4 pack8(float4 a, float4 b) {
    uint4 r;
    r.x = pk2(a.x, a.y); r.y = pk2(a.z, a.w);
    r.z = pk2(b.x, b.y); r.w = pk2(b.z, b.w);
    return r;
}
__device__ __forceinline__ f32x4 mfma16(uint4 a, uint4 b, f32x4 c) {
    return __builtin_amdgcn_mfma_f32_16x16x32_bf16(
        __builtin_bit_cast(bf16x8, a), __builtin_bit_cast(bf16x8, b), c, 0, 0, 0);
}

// ---------------------------------------------------------------------------
// GEMM: C[M,N](bf16) = A[M,K] @ B[N,K]^T + bias(f32), optional ReLU.
// ---------------------------------------------------------------------------
__global__ __launch_bounds__(256) void gemm_bt_kernel(
    const void* __restrict__ A, const float* __restrict__ B,
    const float* __restrict__ bias, u16* __restrict__ C,
    int M, int N, int K, int relu, int a_bf)
{
    __shared__ u16 As[128][72];
    __shared__ u16 Bs[128][72];
    const int tid = threadIdx.x;
    const int m0 = blockIdx.y * 128;
    const int n0 = blockIdx.x * 128;
    const int wave = tid >> 6, lane = tid & 63;
    const int wm = (wave >> 1) * 64, wn = (wave & 1) * 64;
    const int lm = lane & 15, quad = lane >> 4;

    f32x4 acc[4][4] = {};

    for (int k0 = 0; k0 < K; k0 += 64) {
        #pragma unroll
        for (int t = 0; t < 4; ++t) {
            int c = tid + t * 256;
            int row = c >> 3, col = (c & 7) * 8;
            uint4 av;
            if (a_bf) {
                av = *(const uint4*)((const u16*)A + (size_t)(m0 + row) * K + k0 + col);
            } else {
                const float* ap = (const float*)A + (size_t)(m0 + row) * K + k0 + col;
                av = pack8(*(const float4*)ap, *(const float4*)(ap + 4));
            }
            *(uint4*)(&As[row][col]) = av;
            const float* bp = B + (size_t)(n0 + row) * K + k0 + col;
            *(uint4*)(&Bs[row][col]) = pack8(*(const float4*)bp, *(const float4*)(bp + 4));
        }
        __syncthreads();
        #pragma unroll
        for (int kk = 0; kk < 2; ++kk) {
            uint4 af[4], bf[4];
            #pragma unroll
            for (int i = 0; i < 4; ++i)
                af[i] = *(const uint4*)(&As[wm + i * 16 + lm][kk * 32 + quad * 8]);
            #pragma unroll
            for (int j = 0; j < 4; ++j)
                bf[j] = *(const uint4*)(&Bs[wn + j * 16 + lm][kk * 32 + quad * 8]);
            #pragma unroll
            for (int i = 0; i < 4; ++i)
                #pragma unroll
                for (int j = 0; j < 4; ++j)
                    acc[i][j] = mfma16(af[i], bf[j], acc[i][j]);
        }
        __syncthreads();
    }

    #pragma unroll
    for (int j = 0; j < 4; ++j) {
        int cg = n0 + wn + j * 16 + lm;
        float bv = bias ? bias[cg] : 0.f;
        #pragma unroll
        for (int i = 0; i < 4; ++i) {
            #pragma unroll
            for (int r = 0; r < 4; ++r) {
                int rg = m0 + wm + i * 16 + quad * 4 + r;
                float v = acc[i][j][r] + bv;
                if (relu) v = fmaxf(v, 0.f);
                C[(size_t)rg * N + cg] = f2bf(v);
            }
        }
    }
}

// ---------------------------------------------------------------------------
// Fused residual add + LayerNorm over D=512.
// ---------------------------------------------------------------------------
__global__ __launch_bounds__(256) void add_ln_kernel(
    const u16* __restrict__ a, const void* __restrict__ r,
    const float* __restrict__ g, const float* __restrict__ be,
    void* __restrict__ out, int r_f32, int out_f32)
{
    const int row = blockIdx.x, tid = threadIdx.x;
    u32 av = *(const u32*)(a + (size_t)row * 512 + tid * 2);
    float r0, r1;
    if (r_f32) {
        float2 rv = *(const float2*)((const float*)r + (size_t)row * 512 + tid * 2);
        r0 = rv.x; r1 = rv.y;
    } else {
        u32 rv = *(const u32*)((const u16*)r + (size_t)row * 512 + tid * 2);
        r0 = b2f((u16)(rv & 0xFFFFu)); r1 = b2f((u16)(rv >> 16));
    }
    float v0 = b2f((u16)(av & 0xFFFFu)) + r0;
    float v1 = b2f((u16)(av >> 16)) + r1;
    float s = v0 + v1, q = v0 * v0 + v1 * v1;
    #pragma unroll
    for (int m = 1; m < 64; m <<= 1) { s += __shfl_xor(s, m); q += __shfl_xor(q, m); }
    __shared__ float ss[4], qq[4];
    int wave = tid >> 6, lane = tid & 63;
    if (lane == 0) { ss[wave] = s; qq[wave] = q; }
    __syncthreads();
    s = ss[0] + ss[1] + ss[2] + ss[3];
    q = qq[0] + qq[1] + qq[2] + qq[3];
    float mean = s * (1.f / 512.f);
    float var = q * (1.f / 512.f) - mean * mean;
    float rstd = rsqrtf(var + 1e-5f);
    float2 gv = *(const float2*)(g + tid * 2);
    float2 bv = *(const float2*)(be + tid * 2);
    float o0 = (v0 - mean) * rstd * gv.x + bv.x;
    float o1 = (v1 - mean) * rstd * gv.y + bv.y;
    if (out_f32) {
        float2 ov; ov.x = o0; ov.y = o1;
        *(float2*)((float*)out + (size_t)row * 512 + tid * 2) = ov;
    } else {
        *(u32*)((u16*)out + (size_t)row * 512 + tid * 2) = pk2(o0, o1);
    }
}

// ---------------------------------------------------------------------------
// Self-attention, full MFMA flash kernel.
// Computes S^T = K·Q^T per 64-key chunk (K = A-operand from LDS, Q = B-operand
// in registers), online softmax on registers (each lane owns q-row lm), then
// PV via MFMA with P redistributed in-register by bpermute shuffles and V
// staged transposed in LDS. Block = 128 thr (2 waves × 32 q-rows).
// ---------------------------------------------------------------------------
__global__ __launch_bounds__(128) void self_attn_kernel(
    const u16* __restrict__ qkv, u16* __restrict__ o)
{
    const int qb = blockIdx.x;          // 0..15, 64 q-rows per block
    const int bh = blockIdx.y;          // 0..31
    const int b = bh >> 3, h = bh & 7;
    const int tid = threadIdx.x;        // 0..127
    const int lane = tid & 63, wave = tid >> 6;
    const int lm = lane & 15, quad = lane >> 4;

    __shared__ u16 Ks[64][72];          // [key][d], +8 pad (gemm-proven pattern)
    __shared__ u16 Vt[64][72];          // [hd][key], transposed V

    // Q as B-fragment: B[k=d][n=qrow]: lane n=lm -> qrow, k = kh*32+quad*8+j
    uint4 qf[2][2];
    #pragma unroll
    for (int g = 0; g < 2; ++g) {
        int row = qb * 64 + wave * 32 + g * 16 + lm;
        const u16* qp = qkv + ((size_t)row * BATCH + b) * 1536 + h * 64;
        qf[g][0] = *(const uint4*)(qp + quad * 8);
        qf[g][1] = *(const uint4*)(qp + 32 + quad * 8);
    }

    f32x4 o4[2][4] = {};                // O[qrow=quad*4+r][hd=t*16+lm]
    float m_s[2] = {-1e30f, -1e30f};    // running max (scaled units), row lm
    float l_s[2] = {0.f, 0.f};

    for (int c0 = 0; c0 < 1024; c0 += 64) {
        // --- stage K chunk [64key][64d], coalesced b128 ---
        #pragma unroll
        for (int i = 0; i < 4; ++i) {
            int c = tid + i * 128;
            int krow = c >> 3, d0 = (c & 7) * 8;
            *(uint4*)(&Ks[krow][d0]) = *(const uint4*)(
                qkv + ((size_t)(c0 + krow) * BATCH + b) * 1536 + 512 + h * 64 + d0);
        }
        // --- stage V transposed: key-per-lane -> 2-way-free u16 LDS writes ---
        #pragma unroll
        for (int i = 0; i < 4; ++i) {
            int c = tid + i * 128;
            int key = c & 63, dv = (c >> 6) * 8;
            uint4 u = *(const uint4*)(
                qkv + ((size_t)(c0 + key) * BATCH + b) * 1536 + 1024 + h * 64 + dv);
            Vt[dv + 0][key] = (u16)(u.x & 0xFFFFu);
            Vt[dv + 1][key] = (u16)(u.x >> 16);
            Vt[dv + 2][key] = (u16)(u.y & 0xFFFFu);
            Vt[dv + 3][key] = (u16)(u.y >> 16);
            Vt[dv + 4][key] = (u16)(u.z & 0xFFFFu);
            Vt[dv + 5][key] = (u16)(u.z >> 16);
            Vt[dv + 6][key] = (u16)(u.w & 0xFFFFu);
            Vt[dv + 7][key] = (u16)(u.w >> 16);
        }
        __syncthreads();

        // --- S^T = K·Q^T: lane holds S[key=16t+quad*4+r][qrow=lm] ---
        f32x4 s[2][4] = {};
        #pragma unroll
        for (int t = 0; t < 4; ++t) {
            uint4 k0 = *(const uint4*)(&Ks[t * 16 + lm][quad * 8]);
            uint4 k1 = *(const uint4*)(&Ks[t * 16 + lm][32 + quad * 8]);
            s[0][t] = mfma16(k0, qf[0][0], s[0][t]);
            s[0][t] = mfma16(k1, qf[0][1], s[0][t]);
            s[1][t] = mfma16(k0, qf[1][0], s[1][t]);
            s[1][t] = mfma16(k1, qf[1][1], s[1][t]);
        }

        // --- online softmax (row owned by lm across 4 quads) ---
        u32 pkx[2][4], pky[2][4];
        #pragma unroll
        for (int g = 0; g < 2; ++g) {
            float mx = -1e30f;
            #pragma unroll
            for (int t = 0; t < 4; ++t)
                #pragma unroll
                for (int r = 0; r < 4; ++r) {
                    s[g][t][r] *= SCALE_ATTN;
                    mx = fmaxf(mx, s[g][t][r]);
                }
            mx = fmaxf(mx, __shfl_xor(mx, 16));
            mx = fmaxf(mx, __shfl_xor(mx, 32));
            float mn = fmaxf(m_s[g], mx);
            float alpha = __expf(m_s[g] - mn);
            m_s[g] = mn;
            float ps = 0.f;
            #pragma unroll
            for (int t = 0; t < 4; ++t) {
                float p0 = __expf(s[g][t][0] - mn);
                float p1 = __expf(s[g][t][1] - mn);
                float p2 = __expf(s[g][t][2] - mn);
                float p3 = __expf(s[g][t][3] - mn);
                ps += (p0 + p1) + (p2 + p3);
                pkx[g][t] = pk2t(p0, p1);
                pky[g][t] = pk2t(p2, p3);
            }
            ps += __shfl_xor(ps, 16);
            ps += __shfl_xor(ps, 32);
            l_s[g] = l_s[g] * alpha + ps;
            // alpha for O rows quad*4+r lives in lane lm=quad*4+r
            float av[4];
            #pragma unroll
            for (int r = 0; r < 4; ++r) av[r] = __shfl(alpha, quad * 20 + r);
            #pragma unroll
            for (int t = 0; t < 4; ++t)
                #pragma unroll
                for (int r = 0; r < 4; ++r) o4[g][t][r] *= av[r];
        }

        // --- PV: P-frag A[m=lm][k=key] built via shuffles; V-frag from Vt ---
        #pragma unroll
        for (int kh = 0; kh < 2; ++kh) {
            uint4 pf[2];
            int src1 = lm + 32 * (quad & 1);
            int src2 = src1 + 16;
            #pragma unroll
            for (int g = 0; g < 2; ++g) {
                u32 xA = (u32)__shfl((int)pkx[g][2 * kh], src1);
                u32 xB = (u32)__shfl((int)pkx[g][2 * kh + 1], src1);
                u32 yA = (u32)__shfl((int)pky[g][2 * kh], src1);
                u32 yB = (u32)__shfl((int)pky[g][2 * kh + 1], src1);
                u32 zA = (u32)__shfl((int)pkx[g][2 * kh], src2);
                u32 zB = (u32)__shfl((int)pkx[g][2 * kh + 1], src2);
                u32 wA = (u32)__shfl((int)pky[g][2 * kh], src2);
                u32 wB = (u32)__shfl((int)pky[g][2 * kh + 1], src2);
                bool hiq = quad >= 2;
                pf[g].x = hiq ? xB : xA;
                pf[g].y = hiq ? yB : yA;
                pf[g].z = hiq ? zB : zA;
                pf[g].w = hiq ? wB : wA;
            }
            #pragma unroll
            for (int t = 0; t < 4; ++t) {
                uint4 vf = *(const uint4*)(&Vt[t * 16 + lm][kh * 32 + quad * 8]);
                o4[0][t] = mfma16(pf[0], vf, o4[0][t]);
                o4[1][t] = mfma16(pf[1], vf, o4[1][t]);
            }
        }
        __syncthreads();
    }

    // --- epilogue: O / l, write bf16 ---
    #pragma unroll
    for (int g = 0; g < 2; ++g) {
        float linv = 1.f / l_s[g];
        float lv[4];
        #pragma unroll
        for (int r = 0; r < 4; ++r) lv[r] = __shfl(linv, quad * 20 + r);
        #pragma unroll
        for (int t = 0; t < 4; ++t) {
            #pragma unroll
            for (int r = 0; r < 4; ++r) {
                int row = qb * 64 + wave * 32 + g * 16 + quad * 4 + r;
                o[((size_t)row * BATCH + b) * 512 + h * 64 + t * 16 + lm] =
                    f2bf(o4[g][t][r] * lv[r]);
            }
        }
    }
}

// ---------------------------------------------------------------------------
// Sliding-window cross attention: band |i-j|<=16 (33 keys). One thread per
// (t,b,h). bf16 I/O.
// ---------------------------------------------------------------------------
__global__ __launch_bounds__(256) void sw_attn_kernel(
    const u16* __restrict__ q2, const u16* __restrict__ k2,
    const u16* __restrict__ v2, u16* __restrict__ o)
{
    const int idx = blockIdx.x * 256 + threadIdx.x;   // (t*B+b)*8 + h
    const int h = idx & 7;
    const int tb = idx >> 3;
    const int b = tb & 3;
    const int t = tb >> 2;
    const u16* qp = q2 + (size_t)tb * 512 + h * 64;

    float q[64];
    #pragma unroll
    for (int d8 = 0; d8 < 8; ++d8) {
        uint4 u = *(const uint4*)(qp + d8 * 8);
        q[d8 * 8 + 0] = b2f((u16)(u.x & 0xFFFFu)); q[d8 * 8 + 1] = b2f((u16)(u.x >> 16));
        q[d8 * 8 + 2] = b2f((u16)(u.y & 0xFFFFu)); q[d8 * 8 + 3] = b2f((u16)(u.y >> 16));
        q[d8 * 8 + 4] = b2f((u16)(u.z & 0xFFFFu)); q[d8 * 8 + 5] = b2f((u16)(u.z >> 16));
        q[d8 * 8 + 6] = b2f((u16)(u.w & 0xFFFFu)); q[d8 * 8 + 7] = b2f((u16)(u.w >> 16));
    }
    __shared__ float sbuf[256][33];
    float* s = sbuf[threadIdx.x];

    float mx = -3.0e38f;
    for (int w = 0; w < 33; ++w) {
        int j = t - 16 + w;
        bool valid = (j >= 0) && (j < 1024);
        int jc = valid ? j : 0;
        const u16* kp = k2 + ((size_t)jc * BATCH + b) * 512 + h * 64;
        float acc = 0.f;
        #pragma unroll
        for (int d8 = 0; d8 < 8; ++d8) {
            uint4 u = *(const uint4*)(kp + d8 * 8);
            acc += q[d8 * 8 + 0] * b2f((u16)(u.x & 0xFFFFu));
            acc += q[d8 * 8 + 1] * b2f((u16)(u.x >> 16));
            acc += q[d8 * 8 + 2] * b2f((u16)(u.y & 0xFFFFu));
            acc += q[d8 * 8 + 3] * b2f((u16)(u.y >> 16));
            acc += q[d8 * 8 + 4] * b2f((u16)(u.z & 0xFFFFu));
            acc += q[d8 * 8 + 5] * b2f((u16)(u.z >> 16));
            acc += q[d8 * 8 + 6] * b2f((u16)(u.w & 0xFFFFu));
            acc += q[d8 * 8 + 7] * b2f((u16)(u.w >> 16));
        }
        float svw = valid ? acc * SCALE_ATTN : -3.0e38f;
        s[w] = svw;
        mx = fmaxf(mx, svw);
    }
    float l = 0.f;
    for (int w = 0; w < 33; ++w) {
        float p = __expf(s[w] - mx);
        s[w] = p;
        l += p;
    }
    float inv = 1.f / l;

    float ov[64];
    #pragma unroll
    for (int d = 0; d < 64; ++d) ov[d] = 0.f;
    for (int w = 0; w < 33; ++w) {
        int j = t - 16 + w;
        int jc = j < 0 ? 0 : (j > 1023 ? 1023 : j);
        float p = s[w];
        const u16* vp = v2 + ((size_t)jc * BATCH + b) * 512 + h * 64;
        #pragma unroll
        for (int d8 = 0; d8 < 8; ++d8) {
            uint4 u = *(const uint4*)(vp + d8 * 8);
            ov[d8 * 8 + 0] += p * b2f((u16)(u.x & 0xFFFFu));
            ov[d8 * 8 + 1] += p * b2f((u16)(u.x >> 16));
            ov[d8 * 8 + 2] += p * b2f((u16)(u.y & 0xFFFFu));
            ov[d8 * 8 + 3] += p * b2f((u16)(u.y >> 16));
            ov[d8 * 8 + 4] += p * b2f((u16)(u.z & 0xFFFFu));
            ov[d8 * 8 + 5] += p * b2f((u16)(u.z >> 16));
            ov[d8 * 8 + 6] += p * b2f((u16)(u.w & 0xFFFFu));
            ov[d8 * 8 + 7] += p * b2f((u16)(u.w >> 16));
        }
    }
    u16* op = o + (size_t)tb * 512 + h * 64;
    #pragma unroll
    for (int d2 = 0; d2 < 32; ++d2) {
        *(u32*)(op + d2 * 2) = pk2(ov[2 * d2] * inv, ov[2 * d2 + 1] * inv);
    }
}

// ---------------------------------------------------------------------------
// Host orchestration
// ---------------------------------------------------------------------------
static inline void gemm(hipStream_t st, const void* A, const float* B, const float* bias,
                        u16* C, int M, int N, int K, int relu, int a_bf)
{
    dim3 g(N / 128, M / 128);
    gemm_bt_kernel<<<g, dim3(256), 0, st>>>(A, B, bias, C, M, N, K, relu, a_bf);
}

extern "C" void kernel_launch(void* const* d_in, const int* in_sizes, int n_in,
                              void* d_out, int out_size, void* d_ws, size_t ws_size,
                              hipStream_t stream)
{
    const float* tgt        = (const float*)d_in[0];
    const float* memory     = (const float*)d_in[1];
    const float* in_proj_w  = (const float*)d_in[2];
    const float* in_proj_b  = (const float*)d_in[3];
    const float* out_proj_w = (const float*)d_in[4];
    const float* out_proj_b = (const float*)d_in[5];
    const float* sw_q_w = (const float*)d_in[6];
    const float* sw_q_b = (const float*)d_in[7];
    const float* sw_k_w = (const float*)d_in[8];
    const float* sw_k_b = (const float*)d_in[9];
    const float* sw_v_w = (const float*)d_in[10];
    const float* sw_v_b = (const float*)d_in[11];
    const float* sw_o_w = (const float*)d_in[12];
    const float* sw_o_b = (const float*)d_in[13];
    const float* lin1_w = (const float*)d_in[14];
    const float* lin1_b = (const float*)d_in[15];
    const float* lin2_w = (const float*)d_in[16];
    const float* lin2_b = (const float*)d_in[17];
    const float* n1_g = (const float*)d_in[18];
    const float* n1_b = (const float*)d_in[19];
    const float* n2_g = (const float*)d_in[20];
    const float* n2_b = (const float*)d_in[21];
    const float* n3_g = (const float*)d_in[22];
    const float* n3_b = (const float*)d_in[23];

    u16* ws = (u16*)d_ws;
    u16* qkv  = ws;
    u16* x1   = ws + 6291456;
    u16* bufA = ws + 8388608;
    u16* bufB = ws + 10485760;
    u16* x2   = ws + 12582912;
    u16* q2 = qkv;               // reuse qkv region after self-attn
    u16* k2 = qkv + 2097152;
    u16* v2 = qkv + 4194304;
    u16* hbuf = qkv;             // spans qkv+x1 (both dead)

    // 1. QKV projection (A = tgt f32)
    gemm(stream, tgt, in_proj_w, in_proj_b, qkv, NTOK, 1536, 512, 0, 0);
    // 2. self attention (MFMA flash)
    self_attn_kernel<<<dim3(16, 32), dim3(128), 0, stream>>>(qkv, bufA);
    // 3. output projection
    gemm(stream, bufA, out_proj_w, out_proj_b, bufB, NTOK, 512, 512, 0, 1);
    // 4. x1 = LN1(bufB + tgt_f32) -> bf16
    add_ln_kernel<<<dim3(NTOK), dim3(256), 0, stream>>>(bufB, tgt, n1_g, n1_b, x1, 1, 0);
    // 5-7. sliding-window projections
    gemm(stream, x1, sw_q_w, sw_q_b, q2, NTOK, 512, 512, 0, 1);
    gemm(stream, memory, sw_k_w, sw_k_b, k2, NTOK, 512, 512, 0, 0);
    gemm(stream, memory, sw_v_w, sw_v_b, v2, NTOK, 512, 512, 0, 0);
    // 8. sliding-window attention
    sw_attn_kernel<<<dim3(128), dim3(256), 0, stream>>>(q2, k2, v2, bufA);
    // 9. sw output projection
    gemm(stream, bufA, sw_o_w, sw_o_b, bufB, NTOK, 512, 512, 0, 1);
    // 10. x2 = LN2(bufB + x1) -> bf16
    add_ln_kernel<<<dim3(NTOK), dim3(256), 0, stream>>>(bufB, x1, n2_g, n2_b, x2, 0, 0);
    // 11. FFN up + ReLU
    gemm(stream, x2, lin1_w, lin1_b, hbuf, NTOK, 2048, 512, 1, 1);
    // 12. FFN down
    gemm(stream, hbuf, lin2_w, lin2_b, bufA, NTOK, 512, 2048, 0, 1);
    // 13. out = LN3(bufA + x2) -> f32 d_out
    add_ln_kernel<<<dim3(NTOK), dim3(256), 0, stream>>>(bufA, x2, n3_g, n3_b, d_out, 0, 1);
}

// Round 4
// 389.766 us; speedup vs baseline: 1.8304x; 1.2801x over previous
//
#include <hip/hip_runtime.h>

typedef unsigned short u16;
typedef unsigned int u32;

#define BATCH 4
#define NTOK 4096
#define SCALE_ATTN 0.125f

typedef float f32x4 __attribute__((ext_vector_type(4)));
typedef __bf16 bf16x8 __attribute__((ext_vector_type(8)));

__device__ __forceinline__ float b2f(u16 s) { return __uint_as_float(((u32)s) << 16); }
__device__ __forceinline__ u16 f2bf(float f) {
    u32 u = __float_as_uint(f);
    u += 0x7FFFu + ((u >> 16) & 1u);
    return (u16)(u >> 16);
}
__device__ __forceinline__ u32 pk2(float x, float y) {
    return (u32)f2bf(x) | ((u32)f2bf(y) << 16);
}
// truncating pack (attention probabilities only)
__device__ __forceinline__ u32 pk2t(float x, float y) {
    return (__float_as_uint(x) >> 16) | (__float_as_uint(y) & 0xFFFF0000u);
}
__device__ __forceinline__ uint4 pack8(float4 a, float4 b) {
    uint4 r;
    r.x = pk2(a.x, a.y); r.y = pk2(a.z, a.w);
    r.z = pk2(b.x, b.y); r.w = pk2(b.z, b.w);
    return r;
}
__device__ __forceinline__ f32x4 mfma16(uint4 a, uint4 b, f32x4 c) {
    return __builtin_amdgcn_mfma_f32_16x16x32_bf16(
        __builtin_bit_cast(bf16x8, a), __builtin_bit_cast(bf16x8, b), c, 0, 0, 0);
}

// ---------------------------------------------------------------------------
// One-shot f32 -> bf16 conversion of all weights + tgt + memory into a
// contiguous bf16 stream in workspace. 8 elems/thread, exact grid.
// ---------------------------------------------------------------------------
struct CvtTable {
    const float* src[10];
    u32 start[10];      // element offset of each tensor in the dst stream
};
__global__ __launch_bounds__(256) void cvt_bf16_kernel(CvtTable tab, u16* __restrict__ dst)
{
    u32 i8 = (blockIdx.x * 256u + threadIdx.x) * 8u;   // total 8388608 elems
    int t = 0;
    #pragma unroll
    for (int k = 1; k < 10; ++k) t += (i8 >= tab.start[k]) ? 1 : 0;
    const float* s = tab.src[t] + (i8 - tab.start[t]);
    float4 f0 = *(const float4*)s;
    float4 f1 = *(const float4*)(s + 4);
    *(uint4*)(dst + i8) = pack8(f0, f1);
}

// ---------------------------------------------------------------------------
// GEMM: C[M,N](bf16) = A[M,K](bf16) @ B[N,K]^T(bf16) + bias(f32), opt ReLU.
// BK=64, 256 thr (4 waves as 2x2). global_load_lds(16B) staging into a
// fragment-major LDS layout: instr j stages 16 rows x 32 k (1 KB); LDS dest
// j*1024 + lane*16 equals exactly the b128 fragment read order -> conflict-free.
// ---------------------------------------------------------------------------
template<int BM, int BN>
__global__ __launch_bounds__(256) void gemm_lds_kernel(
    const u16* __restrict__ A, const u16* __restrict__ B,
    const float* __restrict__ bias, u16* __restrict__ C,
    int M, int N, int K, int relu)
{
    constexpr int WMF = BM / 32;     // 16-row m-frags per wave
    constexpr int WNF = BN / 32;
    constexpr int AIW = BM / 32;     // staging instrs per wave for A (BM/8/4)
    constexpr int BIW = BN / 32;

    __shared__ u16 As[BM * 64];
    __shared__ u16 Bs[BN * 64];

    const int tid = threadIdx.x;
    const int wave = tid >> 6, lane = tid & 63;
    const int lm = lane & 15, quad = lane >> 4;
    const int m0 = blockIdx.y * BM, n0 = blockIdx.x * BN;
    const int wr = wave >> 1, wc = wave & 1;
    const int lk = (lane >> 4) * 8;          // k sub-chunk per lane in staging

    f32x4 acc[WMF][WNF] = {};

    for (int k0 = 0; k0 < K; k0 += 64) {
        #pragma unroll
        for (int t = 0; t < AIW; ++t) {
            int j = wave * AIW + t;
            int i = j >> 1, c = j & 1;       // rowgroup, k-half
            const u16* gp = A + (size_t)(m0 + i * 16 + lm) * K + k0 + c * 32 + lk;
            __builtin_amdgcn_global_load_lds(
                (const __attribute__((address_space(1))) u32*)gp,
                (__attribute__((address_space(3))) u32*)(As + j * 512), 16, 0, 0);
        }
        #pragma unroll
        for (int t = 0; t < BIW; ++t) {
            int j = wave * BIW + t;
            int i = j >> 1, c = j & 1;
            const u16* gp = B + (size_t)(n0 + i * 16 + lm) * K + k0 + c * 32 + lk;
            __builtin_amdgcn_global_load_lds(
                (const __attribute__((address_space(1))) u32*)gp,
                (__attribute__((address_space(3))) u32*)(Bs + j * 512), 16, 0, 0);
        }
        __syncthreads();

        #pragma unroll
        for (int kk = 0; kk < 2; ++kk) {
            uint4 af[WMF], bf[WNF];
            #pragma unroll
            for (int i2 = 0; i2 < WMF; ++i2) {
                int g = wr * WMF + i2;
                af[i2] = *(const uint4*)(As + ((g * 8 + kk * 4 + quad) * 16 + lm) * 8);
            }
            #pragma unroll
            for (int j2 = 0; j2 < WNF; ++j2) {
                int g = wc * WNF + j2;
                bf[j2] = *(const uint4*)(Bs + ((g * 8 + kk * 4 + quad) * 16 + lm) * 8);
            }
            #pragma unroll
            for (int i2 = 0; i2 < WMF; ++i2)
                #pragma unroll
                for (int j2 = 0; j2 < WNF; ++j2)
                    acc[i2][j2] = mfma16(af[i2], bf[j2], acc[i2][j2]);
        }
        __syncthreads();
    }

    #pragma unroll
    for (int j2 = 0; j2 < WNF; ++j2) {
        int cg = n0 + (wc * WNF + j2) * 16 + lm;
        float bv = bias ? bias[cg] : 0.f;
        #pragma unroll
        for (int i2 = 0; i2 < WMF; ++i2) {
            #pragma unroll
            for (int r = 0; r < 4; ++r) {
                int rg = m0 + (wr * WMF + i2) * 16 + quad * 4 + r;
                float v = acc[i2][j2][r] + bv;
                if (relu) v = fmaxf(v, 0.f);
                C[(size_t)rg * N + cg] = f2bf(v);
            }
        }
    }
}

// ---------------------------------------------------------------------------
// Fused residual add + LayerNorm over D=512.
// ---------------------------------------------------------------------------
__global__ __launch_bounds__(256) void add_ln_kernel(
    const u16* __restrict__ a, const void* __restrict__ r,
    const float* __restrict__ g, const float* __restrict__ be,
    void* __restrict__ out, int r_f32, int out_f32)
{
    const int row = blockIdx.x, tid = threadIdx.x;
    u32 av = *(const u32*)(a + (size_t)row * 512 + tid * 2);
    float r0, r1;
    if (r_f32) {
        float2 rv = *(const float2*)((const float*)r + (size_t)row * 512 + tid * 2);
        r0 = rv.x; r1 = rv.y;
    } else {
        u32 rv = *(const u32*)((const u16*)r + (size_t)row * 512 + tid * 2);
        r0 = b2f((u16)(rv & 0xFFFFu)); r1 = b2f((u16)(rv >> 16));
    }
    float v0 = b2f((u16)(av & 0xFFFFu)) + r0;
    float v1 = b2f((u16)(av >> 16)) + r1;
    float s = v0 + v1, q = v0 * v0 + v1 * v1;
    #pragma unroll
    for (int m = 1; m < 64; m <<= 1) { s += __shfl_xor(s, m); q += __shfl_xor(q, m); }
    __shared__ float ss[4], qq[4];
    int wave = tid >> 6, lane = tid & 63;
    if (lane == 0) { ss[wave] = s; qq[wave] = q; }
    __syncthreads();
    s = ss[0] + ss[1] + ss[2] + ss[3];
    q = qq[0] + qq[1] + qq[2] + qq[3];
    float mean = s * (1.f / 512.f);
    float var = q * (1.f / 512.f) - mean * mean;
    float rstd = rsqrtf(var + 1e-5f);
    float2 gv = *(const float2*)(g + tid * 2);
    float2 bv = *(const float2*)(be + tid * 2);
    float o0 = (v0 - mean) * rstd * gv.x + bv.x;
    float o1 = (v1 - mean) * rstd * gv.y + bv.y;
    if (out_f32) {
        float2 ov; ov.x = o0; ov.y = o1;
        *(float2*)((float*)out + (size_t)row * 512 + tid * 2) = ov;
    } else {
        *(u32*)((u16*)out + (size_t)row * 512 + tid * 2) = pk2(o0, o1);
    }
}

// ---------------------------------------------------------------------------
// Self-attention, full MFMA flash kernel (unchanged from round 3).
// ---------------------------------------------------------------------------
__global__ __launch_bounds__(128) void self_attn_kernel(
    const u16* __restrict__ qkv, u16* __restrict__ o)
{
    const int qb = blockIdx.x;
    const int bh = blockIdx.y;
    const int b = bh >> 3, h = bh & 7;
    const int tid = threadIdx.x;
    const int lane = tid & 63, wave = tid >> 6;
    const int lm = lane & 15, quad = lane >> 4;

    __shared__ u16 Ks[64][72];
    __shared__ u16 Vt[64][72];

    uint4 qf[2][2];
    #pragma unroll
    for (int g = 0; g < 2; ++g) {
        int row = qb * 64 + wave * 32 + g * 16 + lm;
        const u16* qp = qkv + ((size_t)row * BATCH + b) * 1536 + h * 64;
        qf[g][0] = *(const uint4*)(qp + quad * 8);
        qf[g][1] = *(const uint4*)(qp + 32 + quad * 8);
    }

    f32x4 o4[2][4] = {};
    float m_s[2] = {-1e30f, -1e30f};
    float l_s[2] = {0.f, 0.f};

    for (int c0 = 0; c0 < 1024; c0 += 64) {
        #pragma unroll
        for (int i = 0; i < 4; ++i) {
            int c = tid + i * 128;
            int krow = c >> 3, d0 = (c & 7) * 8;
            *(uint4*)(&Ks[krow][d0]) = *(const uint4*)(
                qkv + ((size_t)(c0 + krow) * BATCH + b) * 1536 + 512 + h * 64 + d0);
        }
        #pragma unroll
        for (int i = 0; i < 4; ++i) {
            int c = tid + i * 128;
            int key = c & 63, dv = (c >> 6) * 8;
            uint4 u = *(const uint4*)(
                qkv + ((size_t)(c0 + key) * BATCH + b) * 1536 + 1024 + h * 64 + dv);
            Vt[dv + 0][key] = (u16)(u.x & 0xFFFFu);
            Vt[dv + 1][key] = (u16)(u.x >> 16);
            Vt[dv + 2][key] = (u16)(u.y & 0xFFFFu);
            Vt[dv + 3][key] = (u16)(u.y >> 16);
            Vt[dv + 4][key] = (u16)(u.z & 0xFFFFu);
            Vt[dv + 5][key] = (u16)(u.z >> 16);
            Vt[dv + 6][key] = (u16)(u.w & 0xFFFFu);
            Vt[dv + 7][key] = (u16)(u.w >> 16);
        }
        __syncthreads();

        f32x4 s[2][4] = {};
        #pragma unroll
        for (int t = 0; t < 4; ++t) {
            uint4 k0 = *(const uint4*)(&Ks[t * 16 + lm][quad * 8]);
            uint4 k1 = *(const uint4*)(&Ks[t * 16 + lm][32 + quad * 8]);
            s[0][t] = mfma16(k0, qf[0][0], s[0][t]);
            s[0][t] = mfma16(k1, qf[0][1], s[0][t]);
            s[1][t] = mfma16(k0, qf[1][0], s[1][t]);
            s[1][t] = mfma16(k1, qf[1][1], s[1][t]);
        }

        u32 pkx[2][4], pky[2][4];
        #pragma unroll
        for (int g = 0; g < 2; ++g) {
            float mx = -1e30f;
            #pragma unroll
            for (int t = 0; t < 4; ++t)
                #pragma unroll
                for (int r = 0; r < 4; ++r) {
                    s[g][t][r] *= SCALE_ATTN;
                    mx = fmaxf(mx, s[g][t][r]);
                }
            mx = fmaxf(mx, __shfl_xor(mx, 16));
            mx = fmaxf(mx, __shfl_xor(mx, 32));
            float mn = fmaxf(m_s[g], mx);
            float alpha = __expf(m_s[g] - mn);
            m_s[g] = mn;
            float ps = 0.f;
            #pragma unroll
            for (int t = 0; t < 4; ++t) {
                float p0 = __expf(s[g][t][0] - mn);
                float p1 = __expf(s[g][t][1] - mn);
                float p2 = __expf(s[g][t][2] - mn);
                float p3 = __expf(s[g][t][3] - mn);
                ps += (p0 + p1) + (p2 + p3);
                pkx[g][t] = pk2t(p0, p1);
                pky[g][t] = pk2t(p2, p3);
            }
            ps += __shfl_xor(ps, 16);
            ps += __shfl_xor(ps, 32);
            l_s[g] = l_s[g] * alpha + ps;
            float av[4];
            #pragma unroll
            for (int r = 0; r < 4; ++r) av[r] = __shfl(alpha, quad * 20 + r);
            #pragma unroll
            for (int t = 0; t < 4; ++t)
                #pragma unroll
                for (int r = 0; r < 4; ++r) o4[g][t][r] *= av[r];
        }

        #pragma unroll
        for (int kh = 0; kh < 2; ++kh) {
            uint4 pf[2];
            int src1 = lm + 32 * (quad & 1);
            int src2 = src1 + 16;
            #pragma unroll
            for (int g = 0; g < 2; ++g) {
                u32 xA = (u32)__shfl((int)pkx[g][2 * kh], src1);
                u32 xB = (u32)__shfl((int)pkx[g][2 * kh + 1], src1);
                u32 yA = (u32)__shfl((int)pky[g][2 * kh], src1);
                u32 yB = (u32)__shfl((int)pky[g][2 * kh + 1], src1);
                u32 zA = (u32)__shfl((int)pkx[g][2 * kh], src2);
                u32 zB = (u32)__shfl((int)pkx[g][2 * kh + 1], src2);
                u32 wA = (u32)__shfl((int)pky[g][2 * kh], src2);
                u32 wB = (u32)__shfl((int)pky[g][2 * kh + 1], src2);
                bool hiq = quad >= 2;
                pf[g].x = hiq ? xB : xA;
                pf[g].y = hiq ? yB : yA;
                pf[g].z = hiq ? zB : zA;
                pf[g].w = hiq ? wB : wA;
            }
            #pragma unroll
            for (int t = 0; t < 4; ++t) {
                uint4 vf = *(const uint4*)(&Vt[t * 16 + lm][kh * 32 + quad * 8]);
                o4[0][t] = mfma16(pf[0], vf, o4[0][t]);
                o4[1][t] = mfma16(pf[1], vf, o4[1][t]);
            }
        }
        __syncthreads();
    }

    #pragma unroll
    for (int g = 0; g < 2; ++g) {
        float linv = 1.f / l_s[g];
        float lv[4];
        #pragma unroll
        for (int r = 0; r < 4; ++r) lv[r] = __shfl(linv, quad * 20 + r);
        #pragma unroll
        for (int t = 0; t < 4; ++t) {
            #pragma unroll
            for (int r = 0; r < 4; ++r) {
                int row = qb * 64 + wave * 32 + g * 16 + quad * 4 + r;
                o[((size_t)row * BATCH + b) * 512 + h * 64 + t * 16 + lm] =
                    f2bf(o4[g][t][r] * lv[r]);
            }
        }
    }
}

// ---------------------------------------------------------------------------
// Sliding-window cross attention (unchanged).
// ---------------------------------------------------------------------------
__global__ __launch_bounds__(256) void sw_attn_kernel(
    const u16* __restrict__ q2, const u16* __restrict__ k2,
    const u16* __restrict__ v2, u16* __restrict__ o)
{
    const int idx = blockIdx.x * 256 + threadIdx.x;
    const int h = idx & 7;
    const int tb = idx >> 3;
    const int b = tb & 3;
    const int t = tb >> 2;
    const u16* qp = q2 + (size_t)tb * 512 + h * 64;

    float q[64];
    #pragma unroll
    for (int d8 = 0; d8 < 8; ++d8) {
        uint4 u = *(const uint4*)(qp + d8 * 8);
        q[d8 * 8 + 0] = b2f((u16)(u.x & 0xFFFFu)); q[d8 * 8 + 1] = b2f((u16)(u.x >> 16));
        q[d8 * 8 + 2] = b2f((u16)(u.y & 0xFFFFu)); q[d8 * 8 + 3] = b2f((u16)(u.y >> 16));
        q[d8 * 8 + 4] = b2f((u16)(u.z & 0xFFFFu)); q[d8 * 8 + 5] = b2f((u16)(u.z >> 16));
        q[d8 * 8 + 6] = b2f((u16)(u.w & 0xFFFFu)); q[d8 * 8 + 7] = b2f((u16)(u.w >> 16));
    }
    __shared__ float sbuf[256][33];
    float* s = sbuf[threadIdx.x];

    float mx = -3.0e38f;
    for (int w = 0; w < 33; ++w) {
        int j = t - 16 + w;
        bool valid = (j >= 0) && (j < 1024);
        int jc = valid ? j : 0;
        const u16* kp = k2 + ((size_t)jc * BATCH + b) * 512 + h * 64;
        float acc = 0.f;
        #pragma unroll
        for (int d8 = 0; d8 < 8; ++d8) {
            uint4 u = *(const uint4*)(kp + d8 * 8);
            acc += q[d8 * 8 + 0] * b2f((u16)(u.x & 0xFFFFu));
            acc += q[d8 * 8 + 1] * b2f((u16)(u.x >> 16));
            acc += q[d8 * 8 + 2] * b2f((u16)(u.y & 0xFFFFu));
            acc += q[d8 * 8 + 3] * b2f((u16)(u.y >> 16));
            acc += q[d8 * 8 + 4] * b2f((u16)(u.z & 0xFFFFu));
            acc += q[d8 * 8 + 5] * b2f((u16)(u.z >> 16));
            acc += q[d8 * 8 + 6] * b2f((u16)(u.w & 0xFFFFu));
            acc += q[d8 * 8 + 7] * b2f((u16)(u.w >> 16));
        }
        float svw = valid ? acc * SCALE_ATTN : -3.0e38f;
        s[w] = svw;
        mx = fmaxf(mx, svw);
    }
    float l = 0.f;
    for (int w = 0; w < 33; ++w) {
        float p = __expf(s[w] - mx);
        s[w] = p;
        l += p;
    }
    float inv = 1.f / l;

    float ov[64];
    #pragma unroll
    for (int d = 0; d < 64; ++d) ov[d] = 0.f;
    for (int w = 0; w < 33; ++w) {
        int j = t - 16 + w;
        int jc = j < 0 ? 0 : (j > 1023 ? 1023 : j);
        float p = s[w];
        const u16* vp = v2 + ((size_t)jc * BATCH + b) * 512 + h * 64;
        #pragma unroll
        for (int d8 = 0; d8 < 8; ++d8) {
            uint4 u = *(const uint4*)(vp + d8 * 8);
            ov[d8 * 8 + 0] += p * b2f((u16)(u.x & 0xFFFFu));
            ov[d8 * 8 + 1] += p * b2f((u16)(u.x >> 16));
            ov[d8 * 8 + 2] += p * b2f((u16)(u.y & 0xFFFFu));
            ov[d8 * 8 + 3] += p * b2f((u16)(u.y >> 16));
            ov[d8 * 8 + 4] += p * b2f((u16)(u.z & 0xFFFFu));
            ov[d8 * 8 + 5] += p * b2f((u16)(u.z >> 16));
            ov[d8 * 8 + 6] += p * b2f((u16)(u.w & 0xFFFFu));
            ov[d8 * 8 + 7] += p * b2f((u16)(u.w >> 16));
        }
    }
    u16* op = o + (size_t)tb * 512 + h * 64;
    #pragma unroll
    for (int d2 = 0; d2 < 32; ++d2) {
        *(u32*)(op + d2 * 2) = pk2(ov[2 * d2] * inv, ov[2 * d2 + 1] * inv);
    }
}

// ---------------------------------------------------------------------------
// Host orchestration
// ---------------------------------------------------------------------------
static inline void gemm128(hipStream_t st, const u16* A, const u16* B, const float* bias,
                           u16* C, int M, int N, int K, int relu)
{
    dim3 g(N / 128, M / 128);
    gemm_lds_kernel<128, 128><<<g, dim3(256), 0, st>>>(A, B, bias, C, M, N, K, relu);
}
static inline void gemm64(hipStream_t st, const u16* A, const u16* B, const float* bias,
                          u16* C, int M, int N, int K, int relu)
{
    dim3 g(N / 64, M / 64);
    gemm_lds_kernel<64, 64><<<g, dim3(256), 0, st>>>(A, B, bias, C, M, N, K, relu);
}

extern "C" void kernel_launch(void* const* d_in, const int* in_sizes, int n_in,
                              void* d_out, int out_size, void* d_ws, size_t ws_size,
                              hipStream_t stream)
{
    const float* tgt        = (const float*)d_in[0];
    const float* memory     = (const float*)d_in[1];
    const float* in_proj_w  = (const float*)d_in[2];
    const float* in_proj_b  = (const float*)d_in[3];
    const float* out_proj_w = (const float*)d_in[4];
    const float* out_proj_b = (const float*)d_in[5];
    const float* sw_q_w = (const float*)d_in[6];
    const float* sw_q_b = (const float*)d_in[7];
    const float* sw_k_w = (const float*)d_in[8];
    const float* sw_k_b = (const float*)d_in[9];
    const float* sw_v_w = (const float*)d_in[10];
    const float* sw_v_b = (const float*)d_in[11];
    const float* sw_o_w = (const float*)d_in[12];
    const float* sw_o_b = (const float*)d_in[13];
    const float* lin1_w = (const float*)d_in[14];
    const float* lin1_b = (const float*)d_in[15];
    const float* lin2_w = (const float*)d_in[16];
    const float* lin2_b = (const float*)d_in[17];
    const float* n1_g = (const float*)d_in[18];
    const float* n1_b = (const float*)d_in[19];
    const float* n2_g = (const float*)d_in[20];
    const float* n2_b = (const float*)d_in[21];
    const float* n3_g = (const float*)d_in[22];
    const float* n3_b = (const float*)d_in[23];

    u16* ws = (u16*)d_ws;
    // activation buffers (u16 elems)
    u16* qkv  = ws;                    // 6291456
    u16* x1   = ws + 6291456;          // 2097152
    u16* bufA = ws + 8388608;          // 2097152
    u16* bufB = ws + 10485760;         // 2097152
    u16* x2   = ws + 12582912;         // 2097152
    u16* q2 = qkv;
    u16* k2 = qkv + 2097152;
    u16* v2 = qkv + 4194304;
    u16* hbuf = qkv;                   // spans qkv+x1 (both dead by FFN)

    // bf16 conversions of inputs/weights, contiguous stream at tail
    u16* wc = ws + 14680064;
    u16* tgtb  = wc;                   // 2097152
    u16* memb  = wc + 2097152;         // 2097152
    u16* inpb  = wc + 4194304;         // 786432
    u16* outpb = wc + 4980736;         // 262144
    u16* swqb  = wc + 5242880;
    u16* swkb  = wc + 5505024;
    u16* swvb  = wc + 5767168;
    u16* swob  = wc + 6029312;
    u16* l1b   = wc + 6291456;         // 1048576
    u16* l2b   = wc + 7340032;         // 1048576

    CvtTable tab;
    const float* srcs[10] = {tgt, memory, in_proj_w, out_proj_w, sw_q_w,
                             sw_k_w, sw_v_w, sw_o_w, lin1_w, lin2_w};
    const u32 starts[10] = {0, 2097152, 4194304, 4980736, 5242880,
                            5505024, 5767168, 6029312, 6291456, 7340032};
    for (int i = 0; i < 10; ++i) { tab.src[i] = srcs[i]; tab.start[i] = starts[i]; }
    cvt_bf16_kernel<<<dim3(4096), dim3(256), 0, stream>>>(tab, wc);

    // 1. QKV projection
    gemm128(stream, tgtb, inpb, in_proj_b, qkv, NTOK, 1536, 512, 0);
    // 2. self attention (MFMA flash)
    self_attn_kernel<<<dim3(16, 32), dim3(128), 0, stream>>>(qkv, bufA);
    // 3. output projection
    gemm64(stream, bufA, outpb, out_proj_b, bufB, NTOK, 512, 512, 0);
    // 4. x1 = LN1(bufB + tgt_f32) -> bf16
    add_ln_kernel<<<dim3(NTOK), dim3(256), 0, stream>>>(bufB, tgt, n1_g, n1_b, x1, 1, 0);
    // 5-7. sliding-window projections
    gemm64(stream, x1, swqb, sw_q_b, q2, NTOK, 512, 512, 0);
    gemm64(stream, memb, swkb, sw_k_b, k2, NTOK, 512, 512, 0);
    gemm64(stream, memb, swvb, sw_v_b, v2, NTOK, 512, 512, 0);
    // 8. sliding-window attention
    sw_attn_kernel<<<dim3(128), dim3(256), 0, stream>>>(q2, k2, v2, bufA);
    // 9. sw output projection
    gemm64(stream, bufA, swob, sw_o_b, bufB, NTOK, 512, 512, 0);
    // 10. x2 = LN2(bufB + x1) -> bf16
    add_ln_kernel<<<dim3(NTOK), dim3(256), 0, stream>>>(bufB, x1, n2_g, n2_b, x2, 0, 0);
    // 11. FFN up + ReLU
    gemm128(stream, x2, l1b, lin1_b, hbuf, NTOK, 2048, 512, 1);
    // 12. FFN down
    gemm64(stream, hbuf, l2b, lin2_b, bufA, NTOK, 512, 2048, 0);
    // 13. out = LN3(bufA + x2) -> f32 d_out
    add_ln_kernel<<<dim3(NTOK), dim3(256), 0, stream>>>(bufA, x2, n3_g, n3_b, d_out, 0, 1);
}

// Round 5
// 361.358 us; speedup vs baseline: 1.9742x; 1.0786x over previous
//
#include <hip/hip_runtime.h>

typedef unsigned short u16;
typedef unsigned int u32;

#define BATCH 4
#define NTOK 4096
#define SCALE_ATTN 0.125f

typedef float f32x4 __attribute__((ext_vector_type(4)));
typedef __bf16 bf16x8 __attribute__((ext_vector_type(8)));

__device__ __forceinline__ float b2f(u16 s) { return __uint_as_float(((u32)s) << 16); }
__device__ __forceinline__ u16 f2bf(float f) {
    u32 u = __float_as_uint(f);
    u += 0x7FFFu + ((u >> 16) & 1u);
    return (u16)(u >> 16);
}
__device__ __forceinline__ u32 pk2(float x, float y) {
    return (u32)f2bf(x) | ((u32)f2bf(y) << 16);
}
// truncating pack (attention probabilities only)
__device__ __forceinline__ u32 pk2t(float x, float y) {
    return (__float_as_uint(x) >> 16) | (__float_as_uint(y) & 0xFFFF0000u);
}
__device__ __forceinline__ uint4 pack8(float4 a, float4 b) {
    uint4 r;
    r.x = pk2(a.x, a.y); r.y = pk2(a.z, a.w);
    r.z = pk2(b.x, b.y); r.w = pk2(b.z, b.w);
    return r;
}
__device__ __forceinline__ f32x4 mfma16(uint4 a, uint4 b, f32x4 c) {
    return __builtin_amdgcn_mfma_f32_16x16x32_bf16(
        __builtin_bit_cast(bf16x8, a), __builtin_bit_cast(bf16x8, b), c, 0, 0, 0);
}

// ---------------------------------------------------------------------------
// One-shot f32 -> bf16 conversion of all weights + tgt + memory.
// ---------------------------------------------------------------------------
struct CvtTable {
    const float* src[10];
    u32 start[10];
};
__global__ __launch_bounds__(256) void cvt_bf16_kernel(CvtTable tab, u16* __restrict__ dst)
{
    u32 i8 = (blockIdx.x * 256u + threadIdx.x) * 8u;
    int t = 0;
    #pragma unroll
    for (int k = 1; k < 10; ++k) t += (i8 >= tab.start[k]) ? 1 : 0;
    const float* s = tab.src[t] + (i8 - tab.start[t]);
    float4 f0 = *(const float4*)s;
    float4 f1 = *(const float4*)(s + 4);
    *(uint4*)(dst + i8) = pack8(f0, f1);
}

// ---------------------------------------------------------------------------
// GEMM: C[M,N](bf16) = A[M,K](bf16) @ B[N,K]^T(bf16) + bias(f32), opt ReLU.
// global_load_lds(16B) staging, fragment-major LDS layout (conflict-free).
// ---------------------------------------------------------------------------
template<int BM, int BN>
__global__ __launch_bounds__(256) void gemm_lds_kernel(
    const u16* __restrict__ A, const u16* __restrict__ B,
    const float* __restrict__ bias, u16* __restrict__ C,
    int M, int N, int K, int relu)
{
    constexpr int WMF = BM / 32;
    constexpr int WNF = BN / 32;
    constexpr int AIW = BM / 32;
    constexpr int BIW = BN / 32;

    __shared__ u16 As[BM * 64];
    __shared__ u16 Bs[BN * 64];

    const int tid = threadIdx.x;
    const int wave = tid >> 6, lane = tid & 63;
    const int lm = lane & 15, quad = lane >> 4;
    const int m0 = blockIdx.y * BM, n0 = blockIdx.x * BN;
    const int wr = wave >> 1, wc = wave & 1;
    const int lk = (lane >> 4) * 8;

    f32x4 acc[WMF][WNF] = {};

    for (int k0 = 0; k0 < K; k0 += 64) {
        #pragma unroll
        for (int t = 0; t < AIW; ++t) {
            int j = wave * AIW + t;
            int i = j >> 1, c = j & 1;
            const u16* gp = A + (size_t)(m0 + i * 16 + lm) * K + k0 + c * 32 + lk;
            __builtin_amdgcn_global_load_lds(
                (const __attribute__((address_space(1))) u32*)gp,
                (__attribute__((address_space(3))) u32*)(As + j * 512), 16, 0, 0);
        }
        #pragma unroll
        for (int t = 0; t < BIW; ++t) {
            int j = wave * BIW + t;
            int i = j >> 1, c = j & 1;
            const u16* gp = B + (size_t)(n0 + i * 16 + lm) * K + k0 + c * 32 + lk;
            __builtin_amdgcn_global_load_lds(
                (const __attribute__((address_space(1))) u32*)gp,
                (__attribute__((address_space(3))) u32*)(Bs + j * 512), 16, 0, 0);
        }
        __syncthreads();

        #pragma unroll
        for (int kk = 0; kk < 2; ++kk) {
            uint4 af[WMF], bf[WNF];
            #pragma unroll
            for (int i2 = 0; i2 < WMF; ++i2) {
                int g = wr * WMF + i2;
                af[i2] = *(const uint4*)(As + ((g * 8 + kk * 4 + quad) * 16 + lm) * 8);
            }
            #pragma unroll
            for (int j2 = 0; j2 < WNF; ++j2) {
                int g = wc * WNF + j2;
                bf[j2] = *(const uint4*)(Bs + ((g * 8 + kk * 4 + quad) * 16 + lm) * 8);
            }
            #pragma unroll
            for (int i2 = 0; i2 < WMF; ++i2)
                #pragma unroll
                for (int j2 = 0; j2 < WNF; ++j2)
                    acc[i2][j2] = mfma16(af[i2], bf[j2], acc[i2][j2]);
        }
        __syncthreads();
    }

    #pragma unroll
    for (int j2 = 0; j2 < WNF; ++j2) {
        int cg = n0 + (wc * WNF + j2) * 16 + lm;
        float bv = bias ? bias[cg] : 0.f;
        #pragma unroll
        for (int i2 = 0; i2 < WMF; ++i2) {
            #pragma unroll
            for (int r = 0; r < 4; ++r) {
                int rg = m0 + (wr * WMF + i2) * 16 + quad * 4 + r;
                float v = acc[i2][j2][r] + bv;
                if (relu) v = fmaxf(v, 0.f);
                C[(size_t)rg * N + cg] = f2bf(v);
            }
        }
    }
}

// ---------------------------------------------------------------------------
// Fused residual add + LayerNorm over D=512.
// ---------------------------------------------------------------------------
__global__ __launch_bounds__(256) void add_ln_kernel(
    const u16* __restrict__ a, const void* __restrict__ r,
    const float* __restrict__ g, const float* __restrict__ be,
    void* __restrict__ out, int r_f32, int out_f32)
{
    const int row = blockIdx.x, tid = threadIdx.x;
    u32 av = *(const u32*)(a + (size_t)row * 512 + tid * 2);
    float r0, r1;
    if (r_f32) {
        float2 rv = *(const float2*)((const float*)r + (size_t)row * 512 + tid * 2);
        r0 = rv.x; r1 = rv.y;
    } else {
        u32 rv = *(const u32*)((const u16*)r + (size_t)row * 512 + tid * 2);
        r0 = b2f((u16)(rv & 0xFFFFu)); r1 = b2f((u16)(rv >> 16));
    }
    float v0 = b2f((u16)(av & 0xFFFFu)) + r0;
    float v1 = b2f((u16)(av >> 16)) + r1;
    float s = v0 + v1, q = v0 * v0 + v1 * v1;
    #pragma unroll
    for (int m = 1; m < 64; m <<= 1) { s += __shfl_xor(s, m); q += __shfl_xor(q, m); }
    __shared__ float ss[4], qq[4];
    int wave = tid >> 6, lane = tid & 63;
    if (lane == 0) { ss[wave] = s; qq[wave] = q; }
    __syncthreads();
    s = ss[0] + ss[1] + ss[2] + ss[3];
    q = qq[0] + qq[1] + qq[2] + qq[3];
    float mean = s * (1.f / 512.f);
    float var = q * (1.f / 512.f) - mean * mean;
    float rstd = rsqrtf(var + 1e-5f);
    float2 gv = *(const float2*)(g + tid * 2);
    float2 bv = *(const float2*)(be + tid * 2);
    float o0 = (v0 - mean) * rstd * gv.x + bv.x;
    float o1 = (v1 - mean) * rstd * gv.y + bv.y;
    if (out_f32) {
        float2 ov; ov.x = o0; ov.y = o1;
        *(float2*)((float*)out + (size_t)row * 512 + tid * 2) = ov;
    } else {
        *(u32*)((u16*)out + (size_t)row * 512 + tid * 2) = pk2(o0, o1);
    }
}

// ---------------------------------------------------------------------------
// Self-attention, full MFMA flash kernel.
// Round 5: 256-thr blocks (4 waves), 16 q-rows/wave -> 2048 waves (8/CU).
// K staged via global_load_lds fragment-major; V transposed scalar staging.
// S^T = K*Q^T per 64-key chunk; P redistributed in-register via shuffles.
// ---------------------------------------------------------------------------
__global__ __launch_bounds__(256) void self_attn_kernel(
    const u16* __restrict__ qkv, u16* __restrict__ o)
{
    const int qb = blockIdx.x;          // 0..15 (64 q-rows per block)
    const int bh = blockIdx.y;          // 0..31
    const int b = bh >> 3, h = bh & 7;
    const int tid = threadIdx.x;        // 0..255
    const int lane = tid & 63, wave = tid >> 6;
    const int lm = lane & 15, quad = lane >> 4;

    __shared__ u16 Ks[64 * 64];         // fragment-major (8 KB)
    __shared__ u16 Vt[64][72];          // [hd][key], transposed V (+8 pad)

    // Q as B-fragment for this wave's 16 q-rows
    const int qrow0 = qb * 64 + wave * 16;
    const u16* qp = qkv + ((size_t)(qrow0 + lm) * BATCH + b) * 1536 + h * 64;
    uint4 qf0 = *(const uint4*)(qp + quad * 8);
    uint4 qf1 = *(const uint4*)(qp + 32 + quad * 8);

    f32x4 o4[4] = {};                   // O[qrow=quad*4+r][hd=t*16+lm]
    float m_s = -1e30f, l_s = 0.f;

    for (int c0 = 0; c0 < 1024; c0 += 64) {
        // --- K staging: 8 global_load_lds(16B) instrs, 2 per wave ---
        #pragma unroll
        for (int t2 = 0; t2 < 2; ++t2) {
            int j = wave * 2 + t2;            // 0..7
            int g = j >> 1, c = j & 1;        // key-group, k-half
            const u16* gp = qkv + ((size_t)(c0 + g * 16 + lm) * BATCH + b) * 1536
                            + 512 + h * 64 + c * 32 + quad * 8;
            __builtin_amdgcn_global_load_lds(
                (const __attribute__((address_space(1))) u32*)gp,
                (__attribute__((address_space(3))) u32*)(Ks + j * 512), 16, 0, 0);
        }
        // --- V staging transposed: 256 thr x 2 iters ---
        #pragma unroll
        for (int i = 0; i < 2; ++i) {
            int c = tid + i * 256;            // 0..511
            int key = c & 63, dv = (c >> 6) * 8;
            uint4 u = *(const uint4*)(
                qkv + ((size_t)(c0 + key) * BATCH + b) * 1536 + 1024 + h * 64 + dv);
            Vt[dv + 0][key] = (u16)(u.x & 0xFFFFu);
            Vt[dv + 1][key] = (u16)(u.x >> 16);
            Vt[dv + 2][key] = (u16)(u.y & 0xFFFFu);
            Vt[dv + 3][key] = (u16)(u.y >> 16);
            Vt[dv + 4][key] = (u16)(u.z & 0xFFFFu);
            Vt[dv + 5][key] = (u16)(u.z >> 16);
            Vt[dv + 6][key] = (u16)(u.w & 0xFFFFu);
            Vt[dv + 7][key] = (u16)(u.w >> 16);
        }
        __syncthreads();

        // --- S^T = K*Q^T: lane holds S[key=16t+quad*4+r][qrow=lm] ---
        f32x4 s[4] = {};
        #pragma unroll
        for (int t = 0; t < 4; ++t) {
            uint4 k0 = *(const uint4*)(Ks + t * 1024 + quad * 128 + lm * 8);
            uint4 k1 = *(const uint4*)(Ks + t * 1024 + 512 + quad * 128 + lm * 8);
            s[t] = mfma16(k0, qf0, s[t]);
            s[t] = mfma16(k1, qf1, s[t]);
        }

        // --- online softmax (row owned by lm, replicated across quads) ---
        float mx = -1e30f;
        #pragma unroll
        for (int t = 0; t < 4; ++t)
            #pragma unroll
            for (int r = 0; r < 4; ++r) {
                s[t][r] *= SCALE_ATTN;
                mx = fmaxf(mx, s[t][r]);
            }
        mx = fmaxf(mx, __shfl_xor(mx, 16));
        mx = fmaxf(mx, __shfl_xor(mx, 32));
        float mn = fmaxf(m_s, mx);
        float alpha = __expf(m_s - mn);
        m_s = mn;
        float ps = 0.f;
        u32 pkx[4], pky[4];
        #pragma unroll
        for (int t = 0; t < 4; ++t) {
            float p0 = __expf(s[t][0] - mn);
            float p1 = __expf(s[t][1] - mn);
            float p2 = __expf(s[t][2] - mn);
            float p3 = __expf(s[t][3] - mn);
            ps += (p0 + p1) + (p2 + p3);
            pkx[t] = pk2t(p0, p1);
            pky[t] = pk2t(p2, p3);
        }
        ps += __shfl_xor(ps, 16);
        ps += __shfl_xor(ps, 32);
        l_s = l_s * alpha + ps;
        float av[4];
        #pragma unroll
        for (int r = 0; r < 4; ++r) av[r] = __shfl(alpha, quad * 20 + r);
        #pragma unroll
        for (int t = 0; t < 4; ++t)
            #pragma unroll
            for (int r = 0; r < 4; ++r) o4[t][r] *= av[r];

        // --- PV: P-frag A[m=lm][k=key] via shuffles; V-frag from Vt ---
        #pragma unroll
        for (int kh = 0; kh < 2; ++kh) {
            int src1 = lm + 32 * (quad & 1);
            int src2 = src1 + 16;
            u32 xA = (u32)__shfl((int)pkx[2 * kh], src1);
            u32 xB = (u32)__shfl((int)pkx[2 * kh + 1], src1);
            u32 yA = (u32)__shfl((int)pky[2 * kh], src1);
            u32 yB = (u32)__shfl((int)pky[2 * kh + 1], src1);
            u32 zA = (u32)__shfl((int)pkx[2 * kh], src2);
            u32 zB = (u32)__shfl((int)pkx[2 * kh + 1], src2);
            u32 wA = (u32)__shfl((int)pky[2 * kh], src2);
            u32 wB = (u32)__shfl((int)pky[2 * kh + 1], src2);
            bool hiq = quad >= 2;
            uint4 pf;
            pf.x = hiq ? xB : xA;
            pf.y = hiq ? yB : yA;
            pf.z = hiq ? zB : zA;
            pf.w = hiq ? wB : wA;
            #pragma unroll
            for (int t = 0; t < 4; ++t) {
                uint4 vf = *(const uint4*)(&Vt[t * 16 + lm][kh * 32 + quad * 8]);
                o4[t] = mfma16(pf, vf, o4[t]);
            }
        }
        __syncthreads();
    }

    // --- epilogue ---
    float linv = 1.f / l_s;
    float lv[4];
    #pragma unroll
    for (int r = 0; r < 4; ++r) lv[r] = __shfl(linv, quad * 20 + r);
    #pragma unroll
    for (int t = 0; t < 4; ++t) {
        #pragma unroll
        for (int r = 0; r < 4; ++r) {
            int row = qrow0 + quad * 4 + r;
            o[((size_t)row * BATCH + b) * 512 + h * 64 + t * 16 + lm] =
                f2bf(o4[t][r] * lv[r]);
        }
    }
}

// ---------------------------------------------------------------------------
// Sliding-window cross attention (unchanged).
// ---------------------------------------------------------------------------
__global__ __launch_bounds__(256) void sw_attn_kernel(
    const u16* __restrict__ q2, const u16* __restrict__ k2,
    const u16* __restrict__ v2, u16* __restrict__ o)
{
    const int idx = blockIdx.x * 256 + threadIdx.x;
    const int h = idx & 7;
    const int tb = idx >> 3;
    const int b = tb & 3;
    const int t = tb >> 2;
    const u16* qp = q2 + (size_t)tb * 512 + h * 64;

    float q[64];
    #pragma unroll
    for (int d8 = 0; d8 < 8; ++d8) {
        uint4 u = *(const uint4*)(qp + d8 * 8);
        q[d8 * 8 + 0] = b2f((u16)(u.x & 0xFFFFu)); q[d8 * 8 + 1] = b2f((u16)(u.x >> 16));
        q[d8 * 8 + 2] = b2f((u16)(u.y & 0xFFFFu)); q[d8 * 8 + 3] = b2f((u16)(u.y >> 16));
        q[d8 * 8 + 4] = b2f((u16)(u.z & 0xFFFFu)); q[d8 * 8 + 5] = b2f((u16)(u.z >> 16));
        q[d8 * 8 + 6] = b2f((u16)(u.w & 0xFFFFu)); q[d8 * 8 + 7] = b2f((u16)(u.w >> 16));
    }
    __shared__ float sbuf[256][33];
    float* s = sbuf[threadIdx.x];

    float mx = -3.0e38f;
    for (int w = 0; w < 33; ++w) {
        int j = t - 16 + w;
        bool valid = (j >= 0) && (j < 1024);
        int jc = valid ? j : 0;
        const u16* kp = k2 + ((size_t)jc * BATCH + b) * 512 + h * 64;
        float acc = 0.f;
        #pragma unroll
        for (int d8 = 0; d8 < 8; ++d8) {
            uint4 u = *(const uint4*)(kp + d8 * 8);
            acc += q[d8 * 8 + 0] * b2f((u16)(u.x & 0xFFFFu));
            acc += q[d8 * 8 + 1] * b2f((u16)(u.x >> 16));
            acc += q[d8 * 8 + 2] * b2f((u16)(u.y & 0xFFFFu));
            acc += q[d8 * 8 + 3] * b2f((u16)(u.y >> 16));
            acc += q[d8 * 8 + 4] * b2f((u16)(u.z & 0xFFFFu));
            acc += q[d8 * 8 + 5] * b2f((u16)(u.z >> 16));
            acc += q[d8 * 8 + 6] * b2f((u16)(u.w & 0xFFFFu));
            acc += q[d8 * 8 + 7] * b2f((u16)(u.w >> 16));
        }
        float svw = valid ? acc * SCALE_ATTN : -3.0e38f;
        s[w] = svw;
        mx = fmaxf(mx, svw);
    }
    float l = 0.f;
    for (int w = 0; w < 33; ++w) {
        float p = __expf(s[w] - mx);
        s[w] = p;
        l += p;
    }
    float inv = 1.f / l;

    float ov[64];
    #pragma unroll
    for (int d = 0; d < 64; ++d) ov[d] = 0.f;
    for (int w = 0; w < 33; ++w) {
        int j = t - 16 + w;
        int jc = j < 0 ? 0 : (j > 1023 ? 1023 : j);
        float p = s[w];
        const u16* vp = v2 + ((size_t)jc * BATCH + b) * 512 + h * 64;
        #pragma unroll
        for (int d8 = 0; d8 < 8; ++d8) {
            uint4 u = *(const uint4*)(vp + d8 * 8);
            ov[d8 * 8 + 0] += p * b2f((u16)(u.x & 0xFFFFu));
            ov[d8 * 8 + 1] += p * b2f((u16)(u.x >> 16));
            ov[d8 * 8 + 2] += p * b2f((u16)(u.y & 0xFFFFu));
            ov[d8 * 8 + 3] += p * b2f((u16)(u.y >> 16));
            ov[d8 * 8 + 4] += p * b2f((u16)(u.z & 0xFFFFu));
            ov[d8 * 8 + 5] += p * b2f((u16)(u.z >> 16));
            ov[d8 * 8 + 6] += p * b2f((u16)(u.w & 0xFFFFu));
            ov[d8 * 8 + 7] += p * b2f((u16)(u.w >> 16));
        }
    }
    u16* op = o + (size_t)tb * 512 + h * 64;
    #pragma unroll
    for (int d2 = 0; d2 < 32; ++d2) {
        *(u32*)(op + d2 * 2) = pk2(ov[2 * d2] * inv, ov[2 * d2 + 1] * inv);
    }
}

// ---------------------------------------------------------------------------
// Host orchestration
// ---------------------------------------------------------------------------
static inline void gemm128(hipStream_t st, const u16* A, const u16* B, const float* bias,
                           u16* C, int M, int N, int K, int relu)
{
    dim3 g(N / 128, M / 128);
    gemm_lds_kernel<128, 128><<<g, dim3(256), 0, st>>>(A, B, bias, C, M, N, K, relu);
}
static inline void gemm64(hipStream_t st, const u16* A, const u16* B, const float* bias,
                          u16* C, int M, int N, int K, int relu)
{
    dim3 g(N / 64, M / 64);
    gemm_lds_kernel<64, 64><<<g, dim3(256), 0, st>>>(A, B, bias, C, M, N, K, relu);
}

extern "C" void kernel_launch(void* const* d_in, const int* in_sizes, int n_in,
                              void* d_out, int out_size, void* d_ws, size_t ws_size,
                              hipStream_t stream)
{
    const float* tgt        = (const float*)d_in[0];
    const float* memory     = (const float*)d_in[1];
    const float* in_proj_w  = (const float*)d_in[2];
    const float* in_proj_b  = (const float*)d_in[3];
    const float* out_proj_w = (const float*)d_in[4];
    const float* out_proj_b = (const float*)d_in[5];
    const float* sw_q_w = (const float*)d_in[6];
    const float* sw_q_b = (const float*)d_in[7];
    const float* sw_k_w = (const float*)d_in[8];
    const float* sw_k_b = (const float*)d_in[9];
    const float* sw_v_w = (const float*)d_in[10];
    const float* sw_v_b = (const float*)d_in[11];
    const float* sw_o_w = (const float*)d_in[12];
    const float* sw_o_b = (const float*)d_in[13];
    const float* lin1_w = (const float*)d_in[14];
    const float* lin1_b = (const float*)d_in[15];
    const float* lin2_w = (const float*)d_in[16];
    const float* lin2_b = (const float*)d_in[17];
    const float* n1_g = (const float*)d_in[18];
    const float* n1_b = (const float*)d_in[19];
    const float* n2_g = (const float*)d_in[20];
    const float* n2_b = (const float*)d_in[21];
    const float* n3_g = (const float*)d_in[22];
    const float* n3_b = (const float*)d_in[23];

    u16* ws = (u16*)d_ws;
    u16* qkv  = ws;                    // 6291456
    u16* x1   = ws + 6291456;          // 2097152
    u16* bufA = ws + 8388608;          // 2097152
    u16* bufB = ws + 10485760;         // 2097152
    u16* x2   = ws + 12582912;         // 2097152
    u16* q2 = qkv;
    u16* k2 = qkv + 2097152;
    u16* v2 = qkv + 4194304;
    u16* hbuf = qkv;

    u16* wc = ws + 14680064;
    u16* tgtb  = wc;
    u16* memb  = wc + 2097152;
    u16* inpb  = wc + 4194304;
    u16* outpb = wc + 4980736;
    u16* swqb  = wc + 5242880;
    u16* swkb  = wc + 5505024;
    u16* swvb  = wc + 5767168;
    u16* swob  = wc + 6029312;
    u16* l1b   = wc + 6291456;
    u16* l2b   = wc + 7340032;

    CvtTable tab;
    const float* srcs[10] = {tgt, memory, in_proj_w, out_proj_w, sw_q_w,
                             sw_k_w, sw_v_w, sw_o_w, lin1_w, lin2_w};
    const u32 starts[10] = {0, 2097152, 4194304, 4980736, 5242880,
                            5505024, 5767168, 6029312, 6291456, 7340032};
    for (int i = 0; i < 10; ++i) { tab.src[i] = srcs[i]; tab.start[i] = starts[i]; }
    cvt_bf16_kernel<<<dim3(4096), dim3(256), 0, stream>>>(tab, wc);

    // 1. QKV projection
    gemm128(stream, tgtb, inpb, in_proj_b, qkv, NTOK, 1536, 512, 0);
    // 2. self attention (MFMA flash, 4-wave blocks)
    self_attn_kernel<<<dim3(16, 32), dim3(256), 0, stream>>>(qkv, bufA);
    // 3. output projection
    gemm64(stream, bufA, outpb, out_proj_b, bufB, NTOK, 512, 512, 0);
    // 4. x1 = LN1(bufB + tgt_f32) -> bf16
    add_ln_kernel<<<dim3(NTOK), dim3(256), 0, stream>>>(bufB, tgt, n1_g, n1_b, x1, 1, 0);
    // 5-7. sliding-window projections
    gemm64(stream, x1, swqb, sw_q_b, q2, NTOK, 512, 512, 0);
    gemm64(stream, memb, swkb, sw_k_b, k2, NTOK, 512, 512, 0);
    gemm64(stream, memb, swvb, sw_v_b, v2, NTOK, 512, 512, 0);
    // 8. sliding-window attention
    sw_attn_kernel<<<dim3(128), dim3(256), 0, stream>>>(q2, k2, v2, bufA);
    // 9. sw output projection
    gemm64(stream, bufA, swob, sw_o_b, bufB, NTOK, 512, 512, 0);
    // 10. x2 = LN2(bufB + x1) -> bf16
    add_ln_kernel<<<dim3(NTOK), dim3(256), 0, stream>>>(bufB, x1, n2_g, n2_b, x2, 0, 0);
    // 11. FFN up + ReLU
    gemm128(stream, x2, l1b, lin1_b, hbuf, NTOK, 2048, 512, 1);
    // 12. FFN down
    gemm64(stream, hbuf, l2b, lin2_b, bufA, NTOK, 512, 2048, 0);
    // 13. out = LN3(bufA + x2) -> f32 d_out
    add_ln_kernel<<<dim3(NTOK), dim3(256), 0, stream>>>(bufA, x2, n3_g, n3_b, d_out, 0, 1);
}

// Round 6
// 308.463 us; speedup vs baseline: 2.3128x; 1.1715x over previous
//
#include <hip/hip_runtime.h>

typedef unsigned short u16;
typedef unsigned int u32;

#define BATCH 4
#define NTOK 4096
#define SCALE_ATTN 0.125f

typedef float f32x4 __attribute__((ext_vector_type(4)));
typedef __bf16 bf16x8 __attribute__((ext_vector_type(8)));

__device__ __forceinline__ float b2f(u16 s) { return __uint_as_float(((u32)s) << 16); }
__device__ __forceinline__ u16 f2bf(float f) {
    u32 u = __float_as_uint(f);
    u += 0x7FFFu + ((u >> 16) & 1u);
    return (u16)(u >> 16);
}
__device__ __forceinline__ u32 pk2(float x, float y) {
    return (u32)f2bf(x) | ((u32)f2bf(y) << 16);
}
// truncating pack (attention probabilities only)
__device__ __forceinline__ u32 pk2t(float x, float y) {
    return (__float_as_uint(x) >> 16) | (__float_as_uint(y) & 0xFFFF0000u);
}
__device__ __forceinline__ uint4 pack8(float4 a, float4 b) {
    uint4 r;
    r.x = pk2(a.x, a.y); r.y = pk2(a.z, a.w);
    r.z = pk2(b.x, b.y); r.w = pk2(b.z, b.w);
    return r;
}
__device__ __forceinline__ f32x4 mfma16(uint4 a, uint4 b, f32x4 c) {
    return __builtin_amdgcn_mfma_f32_16x16x32_bf16(
        __builtin_bit_cast(bf16x8, a), __builtin_bit_cast(bf16x8, b), c, 0, 0, 0);
}

// ---------------------------------------------------------------------------
// One-shot f32 -> bf16 conversion of all weights + tgt + memory.
// ---------------------------------------------------------------------------
struct CvtTable {
    const float* src[10];
    u32 start[10];
};
__global__ __launch_bounds__(256) void cvt_bf16_kernel(CvtTable tab, u16* __restrict__ dst)
{
    u32 i8 = (blockIdx.x * 256u + threadIdx.x) * 8u;
    int t = 0;
    #pragma unroll
    for (int k = 1; k < 10; ++k) t += (i8 >= tab.start[k]) ? 1 : 0;
    const float* s = tab.src[t] + (i8 - tab.start[t]);
    float4 f0 = *(const float4*)s;
    float4 f1 = *(const float4*)(s + 4);
    *(uint4*)(dst + i8) = pack8(f0, f1);
}

// ---------------------------------------------------------------------------
// GEMM: C[M,N](bf16) = A[M,K](bf16) @ B[N,K]^T(bf16) + bias(f32), opt ReLU.
// global_load_lds(16B) staging, fragment-major LDS layout (conflict-free).
// ---------------------------------------------------------------------------
template<int BM, int BN>
__global__ __launch_bounds__(256) void gemm_lds_kernel(
    const u16* __restrict__ A, const u16* __restrict__ B,
    const float* __restrict__ bias, u16* __restrict__ C,
    int M, int N, int K, int relu)
{
    constexpr int WMF = BM / 32;
    constexpr int WNF = BN / 32;
    constexpr int AIW = BM / 32;
    constexpr int BIW = BN / 32;

    __shared__ u16 As[BM * 64];
    __shared__ u16 Bs[BN * 64];

    const int tid = threadIdx.x;
    const int wave = tid >> 6, lane = tid & 63;
    const int lm = lane & 15, quad = lane >> 4;
    const int m0 = blockIdx.y * BM, n0 = blockIdx.x * BN;
    const int wr = wave >> 1, wc = wave & 1;
    const int lk = (lane >> 4) * 8;

    f32x4 acc[WMF][WNF] = {};

    for (int k0 = 0; k0 < K; k0 += 64) {
        #pragma unroll
        for (int t = 0; t < AIW; ++t) {
            int j = wave * AIW + t;
            int i = j >> 1, c = j & 1;
            const u16* gp = A + (size_t)(m0 + i * 16 + lm) * K + k0 + c * 32 + lk;
            __builtin_amdgcn_global_load_lds(
                (const __attribute__((address_space(1))) u32*)gp,
                (__attribute__((address_space(3))) u32*)(As + j * 512), 16, 0, 0);
        }
        #pragma unroll
        for (int t = 0; t < BIW; ++t) {
            int j = wave * BIW + t;
            int i = j >> 1, c = j & 1;
            const u16* gp = B + (size_t)(n0 + i * 16 + lm) * K + k0 + c * 32 + lk;
            __builtin_amdgcn_global_load_lds(
                (const __attribute__((address_space(1))) u32*)gp,
                (__attribute__((address_space(3))) u32*)(Bs + j * 512), 16, 0, 0);
        }
        __syncthreads();

        #pragma unroll
        for (int kk = 0; kk < 2; ++kk) {
            uint4 af[WMF], bf[WNF];
            #pragma unroll
            for (int i2 = 0; i2 < WMF; ++i2) {
                int g = wr * WMF + i2;
                af[i2] = *(const uint4*)(As + ((g * 8 + kk * 4 + quad) * 16 + lm) * 8);
            }
            #pragma unroll
            for (int j2 = 0; j2 < WNF; ++j2) {
                int g = wc * WNF + j2;
                bf[j2] = *(const uint4*)(Bs + ((g * 8 + kk * 4 + quad) * 16 + lm) * 8);
            }
            #pragma unroll
            for (int i2 = 0; i2 < WMF; ++i2)
                #pragma unroll
                for (int j2 = 0; j2 < WNF; ++j2)
                    acc[i2][j2] = mfma16(af[i2], bf[j2], acc[i2][j2]);
        }
        __syncthreads();
    }

    #pragma unroll
    for (int j2 = 0; j2 < WNF; ++j2) {
        int cg = n0 + (wc * WNF + j2) * 16 + lm;
        float bv = bias ? bias[cg] : 0.f;
        #pragma unroll
        for (int i2 = 0; i2 < WMF; ++i2) {
            #pragma unroll
            for (int r = 0; r < 4; ++r) {
                int rg = m0 + (wr * WMF + i2) * 16 + quad * 4 + r;
                float v = acc[i2][j2][r] + bv;
                if (relu) v = fmaxf(v, 0.f);
                C[(size_t)rg * N + cg] = f2bf(v);
            }
        }
    }
}

// ---------------------------------------------------------------------------
// Fused residual add + LayerNorm over D=512.
// ---------------------------------------------------------------------------
__global__ __launch_bounds__(256) void add_ln_kernel(
    const u16* __restrict__ a, const void* __restrict__ r,
    const float* __restrict__ g, const float* __restrict__ be,
    void* __restrict__ out, int r_f32, int out_f32)
{
    const int row = blockIdx.x, tid = threadIdx.x;
    u32 av = *(const u32*)(a + (size_t)row * 512 + tid * 2);
    float r0, r1;
    if (r_f32) {
        float2 rv = *(const float2*)((const float*)r + (size_t)row * 512 + tid * 2);
        r0 = rv.x; r1 = rv.y;
    } else {
        u32 rv = *(const u32*)((const u16*)r + (size_t)row * 512 + tid * 2);
        r0 = b2f((u16)(rv & 0xFFFFu)); r1 = b2f((u16)(rv >> 16));
    }
    float v0 = b2f((u16)(av & 0xFFFFu)) + r0;
    float v1 = b2f((u16)(av >> 16)) + r1;
    float s = v0 + v1, q = v0 * v0 + v1 * v1;
    #pragma unroll
    for (int m = 1; m < 64; m <<= 1) { s += __shfl_xor(s, m); q += __shfl_xor(q, m); }
    __shared__ float ss[4], qq[4];
    int wave = tid >> 6, lane = tid & 63;
    if (lane == 0) { ss[wave] = s; qq[wave] = q; }
    __syncthreads();
    s = ss[0] + ss[1] + ss[2] + ss[3];
    q = qq[0] + qq[1] + qq[2] + qq[3];
    float mean = s * (1.f / 512.f);
    float var = q * (1.f / 512.f) - mean * mean;
    float rstd = rsqrtf(var + 1e-5f);
    float2 gv = *(const float2*)(g + tid * 2);
    float2 bv = *(const float2*)(be + tid * 2);
    float o0 = (v0 - mean) * rstd * gv.x + bv.x;
    float o1 = (v1 - mean) * rstd * gv.y + bv.y;
    if (out_f32) {
        float2 ov; ov.x = o0; ov.y = o1;
        *(float2*)((float*)out + (size_t)row * 512 + tid * 2) = ov;
    } else {
        *(u32*)((u16*)out + (size_t)row * 512 + tid * 2) = pk2(o0, o1);
    }
}

// ---------------------------------------------------------------------------
// Self-attention, full MFMA flash kernel (unchanged from round 5).
// ---------------------------------------------------------------------------
__global__ __launch_bounds__(256) void self_attn_kernel(
    const u16* __restrict__ qkv, u16* __restrict__ o)
{
    const int qb = blockIdx.x;
    const int bh = blockIdx.y;
    const int b = bh >> 3, h = bh & 7;
    const int tid = threadIdx.x;
    const int lane = tid & 63, wave = tid >> 6;
    const int lm = lane & 15, quad = lane >> 4;

    __shared__ u16 Ks[64 * 64];
    __shared__ u16 Vt[64][72];

    const int qrow0 = qb * 64 + wave * 16;
    const u16* qp = qkv + ((size_t)(qrow0 + lm) * BATCH + b) * 1536 + h * 64;
    uint4 qf0 = *(const uint4*)(qp + quad * 8);
    uint4 qf1 = *(const uint4*)(qp + 32 + quad * 8);

    f32x4 o4[4] = {};
    float m_s = -1e30f, l_s = 0.f;

    for (int c0 = 0; c0 < 1024; c0 += 64) {
        #pragma unroll
        for (int t2 = 0; t2 < 2; ++t2) {
            int j = wave * 2 + t2;
            int g = j >> 1, c = j & 1;
            const u16* gp = qkv + ((size_t)(c0 + g * 16 + lm) * BATCH + b) * 1536
                            + 512 + h * 64 + c * 32 + quad * 8;
            __builtin_amdgcn_global_load_lds(
                (const __attribute__((address_space(1))) u32*)gp,
                (__attribute__((address_space(3))) u32*)(Ks + j * 512), 16, 0, 0);
        }
        #pragma unroll
        for (int i = 0; i < 2; ++i) {
            int c = tid + i * 256;
            int key = c & 63, dv = (c >> 6) * 8;
            uint4 u = *(const uint4*)(
                qkv + ((size_t)(c0 + key) * BATCH + b) * 1536 + 1024 + h * 64 + dv);
            Vt[dv + 0][key] = (u16)(u.x & 0xFFFFu);
            Vt[dv + 1][key] = (u16)(u.x >> 16);
            Vt[dv + 2][key] = (u16)(u.y & 0xFFFFu);
            Vt[dv + 3][key] = (u16)(u.y >> 16);
            Vt[dv + 4][key] = (u16)(u.z & 0xFFFFu);
            Vt[dv + 5][key] = (u16)(u.z >> 16);
            Vt[dv + 6][key] = (u16)(u.w & 0xFFFFu);
            Vt[dv + 7][key] = (u16)(u.w >> 16);
        }
        __syncthreads();

        f32x4 s[4] = {};
        #pragma unroll
        for (int t = 0; t < 4; ++t) {
            uint4 k0 = *(const uint4*)(Ks + t * 1024 + quad * 128 + lm * 8);
            uint4 k1 = *(const uint4*)(Ks + t * 1024 + 512 + quad * 128 + lm * 8);
            s[t] = mfma16(k0, qf0, s[t]);
            s[t] = mfma16(k1, qf1, s[t]);
        }

        float mx = -1e30f;
        #pragma unroll
        for (int t = 0; t < 4; ++t)
            #pragma unroll
            for (int r = 0; r < 4; ++r) {
                s[t][r] *= SCALE_ATTN;
                mx = fmaxf(mx, s[t][r]);
            }
        mx = fmaxf(mx, __shfl_xor(mx, 16));
        mx = fmaxf(mx, __shfl_xor(mx, 32));
        float mn = fmaxf(m_s, mx);
        float alpha = __expf(m_s - mn);
        m_s = mn;
        float ps = 0.f;
        u32 pkx[4], pky[4];
        #pragma unroll
        for (int t = 0; t < 4; ++t) {
            float p0 = __expf(s[t][0] - mn);
            float p1 = __expf(s[t][1] - mn);
            float p2 = __expf(s[t][2] - mn);
            float p3 = __expf(s[t][3] - mn);
            ps += (p0 + p1) + (p2 + p3);
            pkx[t] = pk2t(p0, p1);
            pky[t] = pk2t(p2, p3);
        }
        ps += __shfl_xor(ps, 16);
        ps += __shfl_xor(ps, 32);
        l_s = l_s * alpha + ps;
        float av[4];
        #pragma unroll
        for (int r = 0; r < 4; ++r) av[r] = __shfl(alpha, quad * 20 + r);
        #pragma unroll
        for (int t = 0; t < 4; ++t)
            #pragma unroll
            for (int r = 0; r < 4; ++r) o4[t][r] *= av[r];

        #pragma unroll
        for (int kh = 0; kh < 2; ++kh) {
            int src1 = lm + 32 * (quad & 1);
            int src2 = src1 + 16;
            u32 xA = (u32)__shfl((int)pkx[2 * kh], src1);
            u32 xB = (u32)__shfl((int)pkx[2 * kh + 1], src1);
            u32 yA = (u32)__shfl((int)pky[2 * kh], src1);
            u32 yB = (u32)__shfl((int)pky[2 * kh + 1], src1);
            u32 zA = (u32)__shfl((int)pkx[2 * kh], src2);
            u32 zB = (u32)__shfl((int)pkx[2 * kh + 1], src2);
            u32 wA = (u32)__shfl((int)pky[2 * kh], src2);
            u32 wB = (u32)__shfl((int)pky[2 * kh + 1], src2);
            bool hiq = quad >= 2;
            uint4 pf;
            pf.x = hiq ? xB : xA;
            pf.y = hiq ? yB : yA;
            pf.z = hiq ? zB : zA;
            pf.w = hiq ? wB : wA;
            #pragma unroll
            for (int t = 0; t < 4; ++t) {
                uint4 vf = *(const uint4*)(&Vt[t * 16 + lm][kh * 32 + quad * 8]);
                o4[t] = mfma16(pf, vf, o4[t]);
            }
        }
        __syncthreads();
    }

    float linv = 1.f / l_s;
    float lv[4];
    #pragma unroll
    for (int r = 0; r < 4; ++r) lv[r] = __shfl(linv, quad * 20 + r);
    #pragma unroll
    for (int t = 0; t < 4; ++t) {
        #pragma unroll
        for (int r = 0; r < 4; ++r) {
            int row = qrow0 + quad * 4 + r;
            o[((size_t)row * BATCH + b) * 512 + h * 64 + t * 16 + lm] =
                f2bf(o4[t][r] * lv[r]);
        }
    }
}

// ---------------------------------------------------------------------------
// Sliding-window cross attention, MFMA band kernel (round 6).
// Band |i-j|<=16. Block = 64 q-rows x (b,h); 4 waves x 16 q-rows.
// Block stages 112 keys [qb*64-16, qb*64+96): K fragment-major via
// global_load_lds (7 tiles x 2 khalves), V transposed in Vt[64][120].
// Wave w uses the 64-key window at tile offset w (16-aligned).
// Single-pass softmax (no online state). P redistributed via shuffles.
// ---------------------------------------------------------------------------
__global__ __launch_bounds__(256) void sw_attn_kernel(
    const u16* __restrict__ q2, const u16* __restrict__ k2,
    const u16* __restrict__ v2, u16* __restrict__ o)
{
    const int qb = blockIdx.x;          // 0..15
    const int bh = blockIdx.y;          // 0..31
    const int b = bh >> 3, h = bh & 7;
    const int tid = threadIdx.x;
    const int lane = tid & 63, wave = tid >> 6;
    const int lm = lane & 15, quad = lane >> 4;

    __shared__ u16 Ks[14 * 512];        // fragment-major: 7 key-tiles x 2 khalves
    __shared__ u16 Vt[64][120];         // [hd][rel key 0..111], +8 pad

    const int kbase = qb * 64 - 16;     // absolute key of rel index 0
    const int qrow0 = qb * 64 + wave * 16;

    // Q as B-fragment for this wave's 16 q-rows
    const u16* qp = q2 + ((size_t)(qrow0 + lm) * BATCH + b) * 512 + h * 64;
    uint4 qf0 = *(const uint4*)(qp + quad * 8);
    uint4 qf1 = *(const uint4*)(qp + 32 + quad * 8);

    // --- K staging: 14 global_load_lds(16B), up to 4 per wave ---
    #pragma unroll
    for (int t2 = 0; t2 < 4; ++t2) {
        int j = wave * 4 + t2;          // 0..15 (guard < 14, wave-uniform)
        if (j < 14) {
            int g = j >> 1, c = j & 1;
            int key = kbase + g * 16 + lm;
            key = min(max(key, 0), 1023);
            const u16* gp = k2 + ((size_t)key * BATCH + b) * 512 + h * 64
                            + c * 32 + quad * 8;
            __builtin_amdgcn_global_load_lds(
                (const __attribute__((address_space(1))) u32*)gp,
                (__attribute__((address_space(3))) u32*)(Ks + j * 512), 16, 0, 0);
        }
    }
    // --- V staging transposed: 112 keys x 64 hd ---
    #pragma unroll
    for (int i = 0; i < 4; ++i) {
        int c = tid + i * 256;          // guard < 896
        if (c < 896) {
            int key = c >> 3, dv = (c & 7) * 8;
            int j = kbase + key;
            j = min(max(j, 0), 1023);
            uint4 u = *(const uint4*)(v2 + ((size_t)j * BATCH + b) * 512 + h * 64 + dv);
            Vt[dv + 0][key] = (u16)(u.x & 0xFFFFu);
            Vt[dv + 1][key] = (u16)(u.x >> 16);
            Vt[dv + 2][key] = (u16)(u.y & 0xFFFFu);
            Vt[dv + 3][key] = (u16)(u.y >> 16);
            Vt[dv + 4][key] = (u16)(u.z & 0xFFFFu);
            Vt[dv + 5][key] = (u16)(u.z >> 16);
            Vt[dv + 6][key] = (u16)(u.w & 0xFFFFu);
            Vt[dv + 7][key] = (u16)(u.w >> 16);
        }
    }
    __syncthreads();

    // --- S^T = K*Q^T over this wave's 64-key window (tiles w..w+3) ---
    f32x4 s[4] = {};
    #pragma unroll
    for (int t = 0; t < 4; ++t) {
        int tw = wave + t;
        uint4 k0 = *(const uint4*)(Ks + (tw * 2 + 0) * 512 + quad * 128 + lm * 8);
        uint4 k1 = *(const uint4*)(Ks + (tw * 2 + 1) * 512 + quad * 128 + lm * 8);
        s[t] = mfma16(k0, qf0, s[t]);
        s[t] = mfma16(k1, qf1, s[t]);
    }

    // --- mask + single-pass softmax (lane owns q-row lm, keys across quads) ---
    float mx = -1e30f;
    #pragma unroll
    for (int t = 0; t < 4; ++t) {
        #pragma unroll
        for (int r = 0; r < 4; ++r) {
            int kl = t * 16 + quad * 4 + r;       // key-local 0..63
            int jj = qrow0 - 16 + kl;             // absolute key
            int d = kl - lm;                      // i-j = 16-d
            bool valid = (d >= 0) && (d <= 32) && (jj >= 0) && (jj < 1024);
            s[t][r] = valid ? s[t][r] * SCALE_ATTN : -1e30f;
            mx = fmaxf(mx, s[t][r]);
        }
    }
    mx = fmaxf(mx, __shfl_xor(mx, 16));
    mx = fmaxf(mx, __shfl_xor(mx, 32));
    float ps = 0.f;
    u32 pkx[4], pky[4];
    #pragma unroll
    for (int t = 0; t < 4; ++t) {
        float p0 = __expf(s[t][0] - mx);
        float p1 = __expf(s[t][1] - mx);
        float p2 = __expf(s[t][2] - mx);
        float p3 = __expf(s[t][3] - mx);
        ps += (p0 + p1) + (p2 + p3);
        pkx[t] = pk2t(p0, p1);
        pky[t] = pk2t(p2, p3);
    }
    ps += __shfl_xor(ps, 16);
    ps += __shfl_xor(ps, 32);

    // --- PV: P-frag via shuffles; V-frag from Vt at window offset wave*16 ---
    f32x4 o4[4] = {};
    #pragma unroll
    for (int kh = 0; kh < 2; ++kh) {
        int src1 = lm + 32 * (quad & 1);
        int src2 = src1 + 16;
        u32 xA = (u32)__shfl((int)pkx[2 * kh], src1);
        u32 xB = (u32)__shfl((int)pkx[2 * kh + 1], src1);
        u32 yA = (u32)__shfl((int)pky[2 * kh], src1);
        u32 yB = (u32)__shfl((int)pky[2 * kh + 1], src1);
        u32 zA = (u32)__shfl((int)pkx[2 * kh], src2);
        u32 zB = (u32)__shfl((int)pkx[2 * kh + 1], src2);
        u32 wA = (u32)__shfl((int)pky[2 * kh], src2);
        u32 wB = (u32)__shfl((int)pky[2 * kh + 1], src2);
        bool hiq = quad >= 2;
        uint4 pf;
        pf.x = hiq ? xB : xA;
        pf.y = hiq ? yB : yA;
        pf.z = hiq ? zB : zA;
        pf.w = hiq ? wB : wA;
        #pragma unroll
        for (int t = 0; t < 4; ++t) {
            uint4 vf = *(const uint4*)(&Vt[t * 16 + lm][wave * 16 + kh * 32 + quad * 8]);
            o4[t] = mfma16(pf, vf, o4[t]);
        }
    }

    // --- epilogue: O / l ---
    float linv = 1.f / ps;
    float lv[4];
    #pragma unroll
    for (int r = 0; r < 4; ++r) lv[r] = __shfl(linv, quad * 20 + r);
    #pragma unroll
    for (int t = 0; t < 4; ++t) {
        #pragma unroll
        for (int r = 0; r < 4; ++r) {
            int row = qrow0 + quad * 4 + r;
            o[((size_t)row * BATCH + b) * 512 + h * 64 + t * 16 + lm] =
                f2bf(o4[t][r] * lv[r]);
        }
    }
}

// ---------------------------------------------------------------------------
// Host orchestration
// ---------------------------------------------------------------------------
static inline void gemm128(hipStream_t st, const u16* A, const u16* B, const float* bias,
                           u16* C, int M, int N, int K, int relu)
{
    dim3 g(N / 128, M / 128);
    gemm_lds_kernel<128, 128><<<g, dim3(256), 0, st>>>(A, B, bias, C, M, N, K, relu);
}
static inline void gemm64(hipStream_t st, const u16* A, const u16* B, const float* bias,
                          u16* C, int M, int N, int K, int relu)
{
    dim3 g(N / 64, M / 64);
    gemm_lds_kernel<64, 64><<<g, dim3(256), 0, st>>>(A, B, bias, C, M, N, K, relu);
}

extern "C" void kernel_launch(void* const* d_in, const int* in_sizes, int n_in,
                              void* d_out, int out_size, void* d_ws, size_t ws_size,
                              hipStream_t stream)
{
    const float* tgt        = (const float*)d_in[0];
    const float* memory     = (const float*)d_in[1];
    const float* in_proj_w  = (const float*)d_in[2];
    const float* in_proj_b  = (const float*)d_in[3];
    const float* out_proj_w = (const float*)d_in[4];
    const float* out_proj_b = (const float*)d_in[5];
    const float* sw_q_w = (const float*)d_in[6];
    const float* sw_q_b = (const float*)d_in[7];
    const float* sw_k_w = (const float*)d_in[8];
    const float* sw_k_b = (const float*)d_in[9];
    const float* sw_v_w = (const float*)d_in[10];
    const float* sw_v_b = (const float*)d_in[11];
    const float* sw_o_w = (const float*)d_in[12];
    const float* sw_o_b = (const float*)d_in[13];
    const float* lin1_w = (const float*)d_in[14];
    const float* lin1_b = (const float*)d_in[15];
    const float* lin2_w = (const float*)d_in[16];
    const float* lin2_b = (const float*)d_in[17];
    const float* n1_g = (const float*)d_in[18];
    const float* n1_b = (const float*)d_in[19];
    const float* n2_g = (const float*)d_in[20];
    const float* n2_b = (const float*)d_in[21];
    const float* n3_g = (const float*)d_in[22];
    const float* n3_b = (const float*)d_in[23];

    u16* ws = (u16*)d_ws;
    u16* qkv  = ws;                    // 6291456
    u16* x1   = ws + 6291456;          // 2097152
    u16* bufA = ws + 8388608;          // 2097152
    u16* bufB = ws + 10485760;         // 2097152
    u16* x2   = ws + 12582912;         // 2097152
    u16* q2 = qkv;
    u16* k2 = qkv + 2097152;
    u16* v2 = qkv + 4194304;
    u16* hbuf = qkv;

    u16* wc = ws + 14680064;
    u16* tgtb  = wc;
    u16* memb  = wc + 2097152;
    u16* inpb  = wc + 4194304;
    u16* outpb = wc + 4980736;
    u16* swqb  = wc + 5242880;
    u16* swkb  = wc + 5505024;
    u16* swvb  = wc + 5767168;
    u16* swob  = wc + 6029312;
    u16* l1b   = wc + 6291456;
    u16* l2b   = wc + 7340032;

    CvtTable tab;
    const float* srcs[10] = {tgt, memory, in_proj_w, out_proj_w, sw_q_w,
                             sw_k_w, sw_v_w, sw_o_w, lin1_w, lin2_w};
    const u32 starts[10] = {0, 2097152, 4194304, 4980736, 5242880,
                            5505024, 5767168, 6029312, 6291456, 7340032};
    for (int i = 0; i < 10; ++i) { tab.src[i] = srcs[i]; tab.start[i] = starts[i]; }
    cvt_bf16_kernel<<<dim3(4096), dim3(256), 0, stream>>>(tab, wc);

    // 1. QKV projection
    gemm128(stream, tgtb, inpb, in_proj_b, qkv, NTOK, 1536, 512, 0);
    // 2. self attention (MFMA flash)
    self_attn_kernel<<<dim3(16, 32), dim3(256), 0, stream>>>(qkv, bufA);
    // 3. output projection
    gemm64(stream, bufA, outpb, out_proj_b, bufB, NTOK, 512, 512, 0);
    // 4. x1 = LN1(bufB + tgt_f32) -> bf16
    add_ln_kernel<<<dim3(NTOK), dim3(256), 0, stream>>>(bufB, tgt, n1_g, n1_b, x1, 1, 0);
    // 5-7. sliding-window projections
    gemm64(stream, x1, swqb, sw_q_b, q2, NTOK, 512, 512, 0);
    gemm64(stream, memb, swkb, sw_k_b, k2, NTOK, 512, 512, 0);
    gemm64(stream, memb, swvb, sw_v_b, v2, NTOK, 512, 512, 0);
    // 8. sliding-window attention (MFMA band kernel)
    sw_attn_kernel<<<dim3(16, 32), dim3(256), 0, stream>>>(q2, k2, v2, bufA);
    // 9. sw output projection
    gemm64(stream, bufA, swob, sw_o_b, bufB, NTOK, 512, 512, 0);
    // 10. x2 = LN2(bufB + x1) -> bf16
    add_ln_kernel<<<dim3(NTOK), dim3(256), 0, stream>>>(bufB, x1, n2_g, n2_b, x2, 0, 0);
    // 11. FFN up + ReLU
    gemm128(stream, x2, l1b, lin1_b, hbuf, NTOK, 2048, 512, 1);
    // 12. FFN down
    gemm64(stream, hbuf, l2b, lin2_b, bufA, NTOK, 512, 2048, 0);
    // 13. out = LN3(bufA + x2) -> f32 d_out
    add_ln_kernel<<<dim3(NTOK), dim3(256), 0, stream>>>(bufA, x2, n3_g, n3_b, d_out, 0, 1);
}

// Round 7
// 307.281 us; speedup vs baseline: 2.3217x; 1.0038x over previous
//
#include <hip/hip_runtime.h>

typedef unsigned short u16;
typedef unsigned int u32;

#define BATCH 4
#define NTOK 4096
#define SCALE_ATTN 0.125f

typedef float f32x4 __attribute__((ext_vector_type(4)));
typedef __bf16 bf16x8 __attribute__((ext_vector_type(8)));

__device__ __forceinline__ float b2f(u16 s) { return __uint_as_float(((u32)s) << 16); }
__device__ __forceinline__ u16 f2bf(float f) {
    u32 u = __float_as_uint(f);
    u += 0x7FFFu + ((u >> 16) & 1u);
    return (u16)(u >> 16);
}
__device__ __forceinline__ u32 pk2(float x, float y) {
    return (u32)f2bf(x) | ((u32)f2bf(y) << 16);
}
// truncating pack (attention probabilities only)
__device__ __forceinline__ u32 pk2t(float x, float y) {
    return (__float_as_uint(x) >> 16) | (__float_as_uint(y) & 0xFFFF0000u);
}
__device__ __forceinline__ uint4 pack8(float4 a, float4 b) {
    uint4 r;
    r.x = pk2(a.x, a.y); r.y = pk2(a.z, a.w);
    r.z = pk2(b.x, b.y); r.w = pk2(b.z, b.w);
    return r;
}
__device__ __forceinline__ f32x4 mfma16(uint4 a, uint4 b, f32x4 c) {
    return __builtin_amdgcn_mfma_f32_16x16x32_bf16(
        __builtin_bit_cast(bf16x8, a), __builtin_bit_cast(bf16x8, b), c, 0, 0, 0);
}

// ---------------------------------------------------------------------------
// One-shot f32 -> bf16 conversion of all weights + tgt + memory.
// ---------------------------------------------------------------------------
struct CvtTable {
    const float* src[10];
    u32 start[10];
};
__global__ __launch_bounds__(256) void cvt_bf16_kernel(CvtTable tab, u16* __restrict__ dst)
{
    u32 i8 = (blockIdx.x * 256u + threadIdx.x) * 8u;
    int t = 0;
    #pragma unroll
    for (int k = 1; k < 10; ++k) t += (i8 >= tab.start[k]) ? 1 : 0;
    const float* s = tab.src[t] + (i8 - tab.start[t]);
    float4 f0 = *(const float4*)s;
    float4 f1 = *(const float4*)(s + 4);
    *(uint4*)(dst + i8) = pack8(f0, f1);
}

// ---------------------------------------------------------------------------
// GEMM: C[M,N](bf16) = A[M,K](bf16) @ B[N,K]^T(bf16) + bias(f32), opt ReLU.
// global_load_lds(16B) staging, fragment-major LDS layout (conflict-free).
// Round 7: double-buffered K-loop — stage tile k+1 right after the barrier,
// compute tile k; ONE barrier per K-step, loads overlap MFMA.
// Dual bias pointers (cols >= split use bias2) for fused concat GEMMs.
// ---------------------------------------------------------------------------
template<int BM, int BN>
__global__ __launch_bounds__(256) void gemm_lds_kernel(
    const u16* __restrict__ A, const u16* __restrict__ B,
    const float* __restrict__ bias, const float* __restrict__ bias2, int split,
    u16* __restrict__ C, int M, int N, int K, int relu)
{
    constexpr int WMF = BM / 32;
    constexpr int WNF = BN / 32;
    constexpr int AIW = BM / 32;
    constexpr int BIW = BN / 32;

    __shared__ u16 As[2][BM * 64];
    __shared__ u16 Bs[2][BN * 64];

    const int tid = threadIdx.x;
    const int wave = tid >> 6, lane = tid & 63;
    const int lm = lane & 15, quad = lane >> 4;
    const int m0 = blockIdx.y * BM, n0 = blockIdx.x * BN;
    const int wr = wave >> 1, wc = wave & 1;
    const int lk = (lane >> 4) * 8;

    f32x4 acc[WMF][WNF] = {};

    auto stage = [&](int buf, int k0) {
        #pragma unroll
        for (int t = 0; t < AIW; ++t) {
            int j = wave * AIW + t;
            int i = j >> 1, c = j & 1;
            const u16* gp = A + (size_t)(m0 + i * 16 + lm) * K + k0 + c * 32 + lk;
            __builtin_amdgcn_global_load_lds(
                (const __attribute__((address_space(1))) u32*)gp,
                (__attribute__((address_space(3))) u32*)(&As[buf][j * 512]), 16, 0, 0);
        }
        #pragma unroll
        for (int t = 0; t < BIW; ++t) {
            int j = wave * BIW + t;
            int i = j >> 1, c = j & 1;
            const u16* gp = B + (size_t)(n0 + i * 16 + lm) * K + k0 + c * 32 + lk;
            __builtin_amdgcn_global_load_lds(
                (const __attribute__((address_space(1))) u32*)gp,
                (__attribute__((address_space(3))) u32*)(&Bs[buf][j * 512]), 16, 0, 0);
        }
    };

    stage(0, 0);
    int cur = 0;
    for (int k0 = 0; k0 < K; k0 += 64) {
        __syncthreads();                    // drains loads of buf `cur`
        if (k0 + 64 < K) stage(cur ^ 1, k0 + 64);   // overlap with compute
        #pragma unroll
        for (int kk = 0; kk < 2; ++kk) {
            uint4 af[WMF], bf[WNF];
            #pragma unroll
            for (int i2 = 0; i2 < WMF; ++i2) {
                int g = wr * WMF + i2;
                af[i2] = *(const uint4*)(&As[cur][((g * 8 + kk * 4 + quad) * 16 + lm) * 8]);
            }
            #pragma unroll
            for (int j2 = 0; j2 < WNF; ++j2) {
                int g = wc * WNF + j2;
                bf[j2] = *(const uint4*)(&Bs[cur][((g * 8 + kk * 4 + quad) * 16 + lm) * 8]);
            }
            #pragma unroll
            for (int i2 = 0; i2 < WMF; ++i2)
                #pragma unroll
                for (int j2 = 0; j2 < WNF; ++j2)
                    acc[i2][j2] = mfma16(af[i2], bf[j2], acc[i2][j2]);
        }
        cur ^= 1;
    }

    #pragma unroll
    for (int j2 = 0; j2 < WNF; ++j2) {
        int cg = n0 + (wc * WNF + j2) * 16 + lm;
        float bv = (cg < split) ? bias[cg] : bias2[cg - split];
        #pragma unroll
        for (int i2 = 0; i2 < WMF; ++i2) {
            #pragma unroll
            for (int r = 0; r < 4; ++r) {
                int rg = m0 + (wr * WMF + i2) * 16 + quad * 4 + r;
                float v = acc[i2][j2][r] + bv;
                if (relu) v = fmaxf(v, 0.f);
                C[(size_t)rg * N + cg] = f2bf(v);
            }
        }
    }
}

// ---------------------------------------------------------------------------
// Fused residual add + LayerNorm over D=512.
// ---------------------------------------------------------------------------
__global__ __launch_bounds__(256) void add_ln_kernel(
    const u16* __restrict__ a, const void* __restrict__ r,
    const float* __restrict__ g, const float* __restrict__ be,
    void* __restrict__ out, int r_f32, int out_f32)
{
    const int row = blockIdx.x, tid = threadIdx.x;
    u32 av = *(const u32*)(a + (size_t)row * 512 + tid * 2);
    float r0, r1;
    if (r_f32) {
        float2 rv = *(const float2*)((const float*)r + (size_t)row * 512 + tid * 2);
        r0 = rv.x; r1 = rv.y;
    } else {
        u32 rv = *(const u32*)((const u16*)r + (size_t)row * 512 + tid * 2);
        r0 = b2f((u16)(rv & 0xFFFFu)); r1 = b2f((u16)(rv >> 16));
    }
    float v0 = b2f((u16)(av & 0xFFFFu)) + r0;
    float v1 = b2f((u16)(av >> 16)) + r1;
    float s = v0 + v1, q = v0 * v0 + v1 * v1;
    #pragma unroll
    for (int m = 1; m < 64; m <<= 1) { s += __shfl_xor(s, m); q += __shfl_xor(q, m); }
    __shared__ float ss[4], qq[4];
    int wave = tid >> 6, lane = tid & 63;
    if (lane == 0) { ss[wave] = s; qq[wave] = q; }
    __syncthreads();
    s = ss[0] + ss[1] + ss[2] + ss[3];
    q = qq[0] + qq[1] + qq[2] + qq[3];
    float mean = s * (1.f / 512.f);
    float var = q * (1.f / 512.f) - mean * mean;
    float rstd = rsqrtf(var + 1e-5f);
    float2 gv = *(const float2*)(g + tid * 2);
    float2 bv = *(const float2*)(be + tid * 2);
    float o0 = (v0 - mean) * rstd * gv.x + bv.x;
    float o1 = (v1 - mean) * rstd * gv.y + bv.y;
    if (out_f32) {
        float2 ov; ov.x = o0; ov.y = o1;
        *(float2*)((float*)out + (size_t)row * 512 + tid * 2) = ov;
    } else {
        *(u32*)((u16*)out + (size_t)row * 512 + tid * 2) = pk2(o0, o1);
    }
}

// ---------------------------------------------------------------------------
// Self-attention, full MFMA flash kernel (unchanged).
// ---------------------------------------------------------------------------
__global__ __launch_bounds__(256) void self_attn_kernel(
    const u16* __restrict__ qkv, u16* __restrict__ o)
{
    const int qb = blockIdx.x;
    const int bh = blockIdx.y;
    const int b = bh >> 3, h = bh & 7;
    const int tid = threadIdx.x;
    const int lane = tid & 63, wave = tid >> 6;
    const int lm = lane & 15, quad = lane >> 4;

    __shared__ u16 Ks[64 * 64];
    __shared__ u16 Vt[64][72];

    const int qrow0 = qb * 64 + wave * 16;
    const u16* qp = qkv + ((size_t)(qrow0 + lm) * BATCH + b) * 1536 + h * 64;
    uint4 qf0 = *(const uint4*)(qp + quad * 8);
    uint4 qf1 = *(const uint4*)(qp + 32 + quad * 8);

    f32x4 o4[4] = {};
    float m_s = -1e30f, l_s = 0.f;

    for (int c0 = 0; c0 < 1024; c0 += 64) {
        #pragma unroll
        for (int t2 = 0; t2 < 2; ++t2) {
            int j = wave * 2 + t2;
            int g = j >> 1, c = j & 1;
            const u16* gp = qkv + ((size_t)(c0 + g * 16 + lm) * BATCH + b) * 1536
                            + 512 + h * 64 + c * 32 + quad * 8;
            __builtin_amdgcn_global_load_lds(
                (const __attribute__((address_space(1))) u32*)gp,
                (__attribute__((address_space(3))) u32*)(Ks + j * 512), 16, 0, 0);
        }
        #pragma unroll
        for (int i = 0; i < 2; ++i) {
            int c = tid + i * 256;
            int key = c & 63, dv = (c >> 6) * 8;
            uint4 u = *(const uint4*)(
                qkv + ((size_t)(c0 + key) * BATCH + b) * 1536 + 1024 + h * 64 + dv);
            Vt[dv + 0][key] = (u16)(u.x & 0xFFFFu);
            Vt[dv + 1][key] = (u16)(u.x >> 16);
            Vt[dv + 2][key] = (u16)(u.y & 0xFFFFu);
            Vt[dv + 3][key] = (u16)(u.y >> 16);
            Vt[dv + 4][key] = (u16)(u.z & 0xFFFFu);
            Vt[dv + 5][key] = (u16)(u.z >> 16);
            Vt[dv + 6][key] = (u16)(u.w & 0xFFFFu);
            Vt[dv + 7][key] = (u16)(u.w >> 16);
        }
        __syncthreads();

        f32x4 s[4] = {};
        #pragma unroll
        for (int t = 0; t < 4; ++t) {
            uint4 k0 = *(const uint4*)(Ks + t * 1024 + quad * 128 + lm * 8);
            uint4 k1 = *(const uint4*)(Ks + t * 1024 + 512 + quad * 128 + lm * 8);
            s[t] = mfma16(k0, qf0, s[t]);
            s[t] = mfma16(k1, qf1, s[t]);
        }

        float mx = -1e30f;
        #pragma unroll
        for (int t = 0; t < 4; ++t)
            #pragma unroll
            for (int r = 0; r < 4; ++r) {
                s[t][r] *= SCALE_ATTN;
                mx = fmaxf(mx, s[t][r]);
            }
        mx = fmaxf(mx, __shfl_xor(mx, 16));
        mx = fmaxf(mx, __shfl_xor(mx, 32));
        float mn = fmaxf(m_s, mx);
        float alpha = __expf(m_s - mn);
        m_s = mn;
        float ps = 0.f;
        u32 pkx[4], pky[4];
        #pragma unroll
        for (int t = 0; t < 4; ++t) {
            float p0 = __expf(s[t][0] - mn);
            float p1 = __expf(s[t][1] - mn);
            float p2 = __expf(s[t][2] - mn);
            float p3 = __expf(s[t][3] - mn);
            ps += (p0 + p1) + (p2 + p3);
            pkx[t] = pk2t(p0, p1);
            pky[t] = pk2t(p2, p3);
        }
        ps += __shfl_xor(ps, 16);
        ps += __shfl_xor(ps, 32);
        l_s = l_s * alpha + ps;
        float av[4];
        #pragma unroll
        for (int r = 0; r < 4; ++r) av[r] = __shfl(alpha, quad * 20 + r);
        #pragma unroll
        for (int t = 0; t < 4; ++t)
            #pragma unroll
            for (int r = 0; r < 4; ++r) o4[t][r] *= av[r];

        #pragma unroll
        for (int kh = 0; kh < 2; ++kh) {
            int src1 = lm + 32 * (quad & 1);
            int src2 = src1 + 16;
            u32 xA = (u32)__shfl((int)pkx[2 * kh], src1);
            u32 xB = (u32)__shfl((int)pkx[2 * kh + 1], src1);
            u32 yA = (u32)__shfl((int)pky[2 * kh], src1);
            u32 yB = (u32)__shfl((int)pky[2 * kh + 1], src1);
            u32 zA = (u32)__shfl((int)pkx[2 * kh], src2);
            u32 zB = (u32)__shfl((int)pkx[2 * kh + 1], src2);
            u32 wA = (u32)__shfl((int)pky[2 * kh], src2);
            u32 wB = (u32)__shfl((int)pky[2 * kh + 1], src2);
            bool hiq = quad >= 2;
            uint4 pf;
            pf.x = hiq ? xB : xA;
            pf.y = hiq ? yB : yA;
            pf.z = hiq ? zB : zA;
            pf.w = hiq ? wB : wA;
            #pragma unroll
            for (int t = 0; t < 4; ++t) {
                uint4 vf = *(const uint4*)(&Vt[t * 16 + lm][kh * 32 + quad * 8]);
                o4[t] = mfma16(pf, vf, o4[t]);
            }
        }
        __syncthreads();
    }

    float linv = 1.f / l_s;
    float lv[4];
    #pragma unroll
    for (int r = 0; r < 4; ++r) lv[r] = __shfl(linv, quad * 20 + r);
    #pragma unroll
    for (int t = 0; t < 4; ++t) {
        #pragma unroll
        for (int r = 0; r < 4; ++r) {
            int row = qrow0 + quad * 4 + r;
            o[((size_t)row * BATCH + b) * 512 + h * 64 + t * 16 + lm] =
                f2bf(o4[t][r] * lv[r]);
        }
    }
}

// ---------------------------------------------------------------------------
// Sliding-window cross attention, MFMA band kernel.
// Round 7: K/V read from fused kv buffer [4096 rows][1024] (k cols 0..511,
// v cols 512..1023). Otherwise identical to round 6.
// ---------------------------------------------------------------------------
__global__ __launch_bounds__(256) void sw_attn_kernel(
    const u16* __restrict__ q2, const u16* __restrict__ kv, u16* __restrict__ o)
{
    const int qb = blockIdx.x;          // 0..15
    const int bh = blockIdx.y;          // 0..31
    const int b = bh >> 3, h = bh & 7;
    const int tid = threadIdx.x;
    const int lane = tid & 63, wave = tid >> 6;
    const int lm = lane & 15, quad = lane >> 4;

    __shared__ u16 Ks[14 * 512];
    __shared__ u16 Vt[64][120];

    const int kbase = qb * 64 - 16;
    const int qrow0 = qb * 64 + wave * 16;

    const u16* qp = q2 + ((size_t)(qrow0 + lm) * BATCH + b) * 512 + h * 64;
    uint4 qf0 = *(const uint4*)(qp + quad * 8);
    uint4 qf1 = *(const uint4*)(qp + 32 + quad * 8);

    #pragma unroll
    for (int t2 = 0; t2 < 4; ++t2) {
        int j = wave * 4 + t2;
        if (j < 14) {
            int g = j >> 1, c = j & 1;
            int key = kbase + g * 16 + lm;
            key = min(max(key, 0), 1023);
            const u16* gp = kv + ((size_t)key * BATCH + b) * 1024 + h * 64
                            + c * 32 + quad * 8;
            __builtin_amdgcn_global_load_lds(
                (const __attribute__((address_space(1))) u32*)gp,
                (__attribute__((address_space(3))) u32*)(Ks + j * 512), 16, 0, 0);
        }
    }
    #pragma unroll
    for (int i = 0; i < 4; ++i) {
        int c = tid + i * 256;
        if (c < 896) {
            int key = c >> 3, dv = (c & 7) * 8;
            int j = kbase + key;
            j = min(max(j, 0), 1023);
            uint4 u = *(const uint4*)(kv + ((size_t)j * BATCH + b) * 1024 + 512 + h * 64 + dv);
            Vt[dv + 0][key] = (u16)(u.x & 0xFFFFu);
            Vt[dv + 1][key] = (u16)(u.x >> 16);
            Vt[dv + 2][key] = (u16)(u.y & 0xFFFFu);
            Vt[dv + 3][key] = (u16)(u.y >> 16);
            Vt[dv + 4][key] = (u16)(u.z & 0xFFFFu);
            Vt[dv + 5][key] = (u16)(u.z >> 16);
            Vt[dv + 6][key] = (u16)(u.w & 0xFFFFu);
            Vt[dv + 7][key] = (u16)(u.w >> 16);
        }
    }
    __syncthreads();

    f32x4 s[4] = {};
    #pragma unroll
    for (int t = 0; t < 4; ++t) {
        int tw = wave + t;
        uint4 k0 = *(const uint4*)(Ks + (tw * 2 + 0) * 512 + quad * 128 + lm * 8);
        uint4 k1 = *(const uint4*)(Ks + (tw * 2 + 1) * 512 + quad * 128 + lm * 8);
        s[t] = mfma16(k0, qf0, s[t]);
        s[t] = mfma16(k1, qf1, s[t]);
    }

    float mx = -1e30f;
    #pragma unroll
    for (int t = 0; t < 4; ++t) {
        #pragma unroll
        for (int r = 0; r < 4; ++r) {
            int kl = t * 16 + quad * 4 + r;
            int jj = qrow0 - 16 + kl;
            int d = kl - lm;
            bool valid = (d >= 0) && (d <= 32) && (jj >= 0) && (jj < 1024);
            s[t][r] = valid ? s[t][r] * SCALE_ATTN : -1e30f;
            mx = fmaxf(mx, s[t][r]);
        }
    }
    mx = fmaxf(mx, __shfl_xor(mx, 16));
    mx = fmaxf(mx, __shfl_xor(mx, 32));
    float ps = 0.f;
    u32 pkx[4], pky[4];
    #pragma unroll
    for (int t = 0; t < 4; ++t) {
        float p0 = __expf(s[t][0] - mx);
        float p1 = __expf(s[t][1] - mx);
        float p2 = __expf(s[t][2] - mx);
        float p3 = __expf(s[t][3] - mx);
        ps += (p0 + p1) + (p2 + p3);
        pkx[t] = pk2t(p0, p1);
        pky[t] = pk2t(p2, p3);
    }
    ps += __shfl_xor(ps, 16);
    ps += __shfl_xor(ps, 32);

    f32x4 o4[4] = {};
    #pragma unroll
    for (int kh = 0; kh < 2; ++kh) {
        int src1 = lm + 32 * (quad & 1);
        int src2 = src1 + 16;
        u32 xA = (u32)__shfl((int)pkx[2 * kh], src1);
        u32 xB = (u32)__shfl((int)pkx[2 * kh + 1], src1);
        u32 yA = (u32)__shfl((int)pky[2 * kh], src1);
        u32 yB = (u32)__shfl((int)pky[2 * kh + 1], src1);
        u32 zA = (u32)__shfl((int)pkx[2 * kh], src2);
        u32 zB = (u32)__shfl((int)pkx[2 * kh + 1], src2);
        u32 wA = (u32)__shfl((int)pky[2 * kh], src2);
        u32 wB = (u32)__shfl((int)pky[2 * kh + 1], src2);
        bool hiq = quad >= 2;
        uint4 pf;
        pf.x = hiq ? xB : xA;
        pf.y = hiq ? yB : yA;
        pf.z = hiq ? zB : zA;
        pf.w = hiq ? wB : wA;
        #pragma unroll
        for (int t = 0; t < 4; ++t) {
            uint4 vf = *(const uint4*)(&Vt[t * 16 + lm][wave * 16 + kh * 32 + quad * 8]);
            o4[t] = mfma16(pf, vf, o4[t]);
        }
    }

    float linv = 1.f / ps;
    float lv[4];
    #pragma unroll
    for (int r = 0; r < 4; ++r) lv[r] = __shfl(linv, quad * 20 + r);
    #pragma unroll
    for (int t = 0; t < 4; ++t) {
        #pragma unroll
        for (int r = 0; r < 4; ++r) {
            int row = qrow0 + quad * 4 + r;
            o[((size_t)row * BATCH + b) * 512 + h * 64 + t * 16 + lm] =
                f2bf(o4[t][r] * lv[r]);
        }
    }
}

// ---------------------------------------------------------------------------
// Host orchestration
// ---------------------------------------------------------------------------
static inline void gemm128(hipStream_t st, const u16* A, const u16* B,
                           const float* bias, const float* bias2, int split,
                           u16* C, int M, int N, int K, int relu)
{
    dim3 g(N / 128, M / 128);
    gemm_lds_kernel<128, 128><<<g, dim3(256), 0, st>>>(A, B, bias, bias2, split,
                                                       C, M, N, K, relu);
}
static inline void gemm64(hipStream_t st, const u16* A, const u16* B,
                          const float* bias, u16* C, int M, int N, int K, int relu)
{
    dim3 g(N / 64, M / 64);
    gemm_lds_kernel<64, 64><<<g, dim3(256), 0, st>>>(A, B, bias, bias, N,
                                                     C, M, N, K, relu);
}

extern "C" void kernel_launch(void* const* d_in, const int* in_sizes, int n_in,
                              void* d_out, int out_size, void* d_ws, size_t ws_size,
                              hipStream_t stream)
{
    const float* tgt        = (const float*)d_in[0];
    const float* memory     = (const float*)d_in[1];
    const float* in_proj_w  = (const float*)d_in[2];
    const float* in_proj_b  = (const float*)d_in[3];
    const float* out_proj_w = (const float*)d_in[4];
    const float* out_proj_b = (const float*)d_in[5];
    const float* sw_q_w = (const float*)d_in[6];
    const float* sw_q_b = (const float*)d_in[7];
    const float* sw_k_w = (const float*)d_in[8];
    const float* sw_k_b = (const float*)d_in[9];
    const float* sw_v_w = (const float*)d_in[10];
    const float* sw_v_b = (const float*)d_in[11];
    const float* sw_o_w = (const float*)d_in[12];
    const float* sw_o_b = (const float*)d_in[13];
    const float* lin1_w = (const float*)d_in[14];
    const float* lin1_b = (const float*)d_in[15];
    const float* lin2_w = (const float*)d_in[16];
    const float* lin2_b = (const float*)d_in[17];
    const float* n1_g = (const float*)d_in[18];
    const float* n1_b = (const float*)d_in[19];
    const float* n2_g = (const float*)d_in[20];
    const float* n2_b = (const float*)d_in[21];
    const float* n3_g = (const float*)d_in[22];
    const float* n3_b = (const float*)d_in[23];

    u16* ws = (u16*)d_ws;
    u16* qkv  = ws;                    // 6291456
    u16* x1   = ws + 6291456;          // 2097152
    u16* bufA = ws + 8388608;          // 2097152
    u16* bufB = ws + 10485760;         // 2097152
    u16* x2   = ws + 12582912;         // 2097152
    u16* q2 = qkv;                     // 2097152 (reuse qkv region)
    u16* kv = qkv + 2097152;           // 4194304 = [4096][1024] fused k|v
    u16* hbuf = qkv;                   // spans qkv+x1 (both dead by FFN)

    u16* wc = ws + 14680064;
    u16* tgtb  = wc;
    u16* memb  = wc + 2097152;
    u16* inpb  = wc + 4194304;
    u16* outpb = wc + 4980736;
    u16* swqb  = wc + 5242880;
    u16* swkb  = wc + 5505024;         // rows 0..511 = sw_k_w, then sw_v_w (adjacent)
    u16* swvb  = wc + 5767168;
    u16* swob  = wc + 6029312;
    u16* l1b   = wc + 6291456;
    u16* l2b   = wc + 7340032;
    (void)swvb;

    CvtTable tab;
    const float* srcs[10] = {tgt, memory, in_proj_w, out_proj_w, sw_q_w,
                             sw_k_w, sw_v_w, sw_o_w, lin1_w, lin2_w};
    const u32 starts[10] = {0, 2097152, 4194304, 4980736, 5242880,
                            5505024, 5767168, 6029312, 6291456, 7340032};
    for (int i = 0; i < 10; ++i) { tab.src[i] = srcs[i]; tab.start[i] = starts[i]; }
    cvt_bf16_kernel<<<dim3(4096), dim3(256), 0, stream>>>(tab, wc);

    // 1. QKV projection
    gemm128(stream, tgtb, inpb, in_proj_b, in_proj_b, 1536, qkv, NTOK, 1536, 512, 0);
    // 2. self attention (MFMA flash)
    self_attn_kernel<<<dim3(16, 32), dim3(256), 0, stream>>>(qkv, bufA);
    // 3. output projection
    gemm64(stream, bufA, outpb, out_proj_b, bufB, NTOK, 512, 512, 0);
    // 4. x1 = LN1(bufB + tgt_bf16) -> bf16
    add_ln_kernel<<<dim3(NTOK), dim3(256), 0, stream>>>(bufB, tgtb, n1_g, n1_b, x1, 0, 0);
    // 5. sw_q projection
    gemm64(stream, x1, swqb, sw_q_b, q2, NTOK, 512, 512, 0);
    // 6. fused sw_k + sw_v projection -> kv [4096][1024]
    gemm128(stream, memb, swkb, sw_k_b, sw_v_b, 512, kv, NTOK, 1024, 512, 0);
    // 7. sliding-window attention (MFMA band kernel, fused kv input)
    sw_attn_kernel<<<dim3(16, 32), dim3(256), 0, stream>>>(q2, kv, bufA);
    // 8. sw output projection
    gemm64(stream, bufA, swob, sw_o_b, bufB, NTOK, 512, 512, 0);
    // 9. x2 = LN2(bufB + x1) -> bf16
    add_ln_kernel<<<dim3(NTOK), dim3(256), 0, stream>>>(bufB, x1, n2_g, n2_b, x2, 0, 0);
    // 10. FFN up + ReLU
    gemm128(stream, x2, l1b, lin1_b, lin1_b, 2048, hbuf, NTOK, 2048, 512, 1);
    // 11. FFN down
    gemm64(stream, hbuf, l2b, lin2_b, bufA, NTOK, 512, 2048, 0);
    // 12. out = LN3(bufA + x2) -> f32 d_out
    add_ln_kernel<<<dim3(NTOK), dim3(256), 0, stream>>>(bufA, x2, n3_g, n3_b, d_out, 0, 1);
}